// Round 11
// baseline (72.077 us; speedup 1.0000x reference)
//
#include <hip/hip_runtime.h>
#include <math.h>

#define NSEQ   1024
#define HEADS  8
#define DHEAD  64
#define SCALE  0.125f
#define LOG2E  1.4426950408889634f

typedef unsigned int u32;
typedef unsigned short u16;
typedef short short8 __attribute__((ext_vector_type(8)));   // 8 bf16 (4 VGPRs)
typedef __bf16 bf16x2 __attribute__((ext_vector_type(2)));
typedef __bf16 bf16x8 __attribute__((ext_vector_type(8)));
typedef float f32x4  __attribute__((ext_vector_type(4)));
typedef float f32x16 __attribute__((ext_vector_type(16)));

__device__ __forceinline__ u16 f2bf(float f) {
    __bf16 h = (__bf16)f;
    return __builtin_bit_cast(u16, h);
}
__device__ __forceinline__ u32 pk2(float lo, float hi) {
    bf16x2 v; v[0] = (__bf16)lo; v[1] = (__bf16)hi;
    return __builtin_bit_cast(u32, v);
}
__device__ __forceinline__ short8 cvt8(float4 a, float4 b) {
    bf16x8 v;
    v[0] = (__bf16)a.x; v[1] = (__bf16)a.y; v[2] = (__bf16)a.z; v[3] = (__bf16)a.w;
    v[4] = (__bf16)b.x; v[5] = (__bf16)b.y; v[6] = (__bf16)b.z; v[7] = (__bf16)b.w;
    return __builtin_bit_cast(short8, v);
}
// no inline-asm exp (R6 lesson: unscheduled TRANS hazard -> nondeterminism)
__device__ __forceinline__ float exp2_fast(float x) {
#if __has_builtin(__builtin_amdgcn_exp2f)
    return __builtin_amdgcn_exp2f(x);
#else
    return exp2f(x);
#endif
}
__device__ __forceinline__ f32x4 mfma16(short8 a, short8 b, f32x4 c) {
    return __builtin_amdgcn_mfma_f32_16x16x32_bf16(a, b, c, 0, 0, 0);
}
__device__ __forceinline__ f32x16 mfma32(short8 a, short8 b, f32x16 c) {
    return __builtin_amdgcn_mfma_f32_32x32x16_bf16(a, b, c, 0, 0, 0);
}

// ---------------------------------------------------------------------------
// prep (weights only): fp32 [K][N] -> bf16 [N][K] transpose-convert.
// blocks [0,192): w_qkv^T; [192,256): w_out^T.
// ---------------------------------------------------------------------------
__global__ __launch_bounds__(256) void prep(const float* __restrict__ wqkv,
                                            const float* __restrict__ wout,
                                            u16* __restrict__ wqkvT,
                                            u16* __restrict__ woutT) {
    __shared__ float T[64][65];
    const int t = threadIdx.x;
    const int bb = blockIdx.x;
    const float* in; u16* outp; int K, N, n0, k0;
    if (bb < 192) {
        in = wqkv; outp = wqkvT; K = 512; N = 1536;
        n0 = (bb % 24) * 64; k0 = (bb / 24) * 64;
    } else {
        int bid = bb - 192;
        in = wout; outp = woutT; K = 512; N = 512;
        n0 = (bid % 8) * 64; k0 = (bid / 8) * 64;
    }
    #pragma unroll
    for (int rep = 0; rep < 4; ++rep) {
        int r = rep * 16 + (t >> 4), c = (t & 15) * 4;
        float4 v = *(const float4*)&in[(size_t)(k0 + r) * N + n0 + c];
        T[r][c + 0] = v.x; T[r][c + 1] = v.y; T[r][c + 2] = v.z; T[r][c + 3] = v.w;
    }
    __syncthreads();
    const int nl = t >> 2, kb = (t & 3) * 16;
    bf16x8 s0, s1;
    #pragma unroll
    for (int e = 0; e < 8; ++e) s0[e] = (__bf16)T[kb + e][nl];
    #pragma unroll
    for (int e = 0; e < 8; ++e) s1[e] = (__bf16)T[kb + 8 + e][nl];
    *(short8*)&outp[(size_t)(n0 + nl) * K + k0 + kb]     = __builtin_bit_cast(short8, s0);
    *(short8*)&outp[(size_t)(n0 + nl) * K + k0 + kb + 8] = __builtin_bit_cast(short8, s1);
}

// ---------------------------------------------------------------------------
// GEMM qkv (R7 structure: BM=128 x BN=64, BK=32, 2D grid, padded LDS) with
// ONE change: A-operand reads x fp32 directly and converts at LDS staging
// (kills the x_bf round-trip).  v path writes C^T -> vT[b,h,d,n].
// ---------------------------------------------------------------------------
__global__ __launch_bounds__(256) void gemm_qkv_mfma(const float* __restrict__ x,
                                                     const u16* __restrict__ wT,
                                                     u16* __restrict__ qb,
                                                     u16* __restrict__ kb,
                                                     u16* __restrict__ vT) {
    __shared__ u16 As[128][40];
    __shared__ u16 Bs[64][40];
    const int t = threadIdx.x, lane = t & 63, w = t >> 6;
    const int wm = w >> 1, wn = w & 1;
    const int l15 = lane & 15, l4 = lane >> 4;
    const int j0 = blockIdx.x * 64, i0 = blockIdx.y * 128;
    const int which = j0 / 512;           // 0=q 1=k 2=v (uniform per block)
    const int b = i0 >> 10;

    f32x4 acc[8];
    #pragma unroll
    for (int i = 0; i < 8; ++i) acc[i] = (f32x4){0.f, 0.f, 0.f, 0.f};

    const int arow = t >> 2, c8 = (t & 3) * 8;

    float4 rax[4];          // A: 2 rows x 8 fp32
    short8 rbv;             // B: 1 row x 8 bf16
    #pragma unroll
    for (int rep = 0; rep < 2; ++rep) {
        rax[rep * 2 + 0] = *(const float4*)&x[(size_t)(i0 + rep * 64 + arow) * 512 + c8];
        rax[rep * 2 + 1] = *(const float4*)&x[(size_t)(i0 + rep * 64 + arow) * 512 + c8 + 4];
    }
    rbv = *(const short8*)&wT[(size_t)(j0 + arow) * 512 + c8];

    for (int kt = 0; kt < 16; ++kt) {
        __syncthreads();
        #pragma unroll
        for (int rep = 0; rep < 2; ++rep)
            *(short8*)&As[rep * 64 + arow][c8] = cvt8(rax[rep * 2 + 0], rax[rep * 2 + 1]);
        *(short8*)&Bs[arow][c8] = rbv;
        __syncthreads();
        if (kt < 15) {
            int k0 = (kt + 1) * 32;
            #pragma unroll
            for (int rep = 0; rep < 2; ++rep) {
                rax[rep * 2 + 0] = *(const float4*)&x[(size_t)(i0 + rep * 64 + arow) * 512 + k0 + c8];
                rax[rep * 2 + 1] = *(const float4*)&x[(size_t)(i0 + rep * 64 + arow) * 512 + k0 + c8 + 4];
            }
            rbv = *(const short8*)&wT[(size_t)(j0 + arow) * 512 + k0 + c8];
        }
        if (which < 2) {
            short8 af[4], bf[2];
            #pragma unroll
            for (int m = 0; m < 4; ++m)
                af[m] = *(const short8*)&As[wm * 64 + m * 16 + l15][l4 * 8];
            #pragma unroll
            for (int n = 0; n < 2; ++n)
                bf[n] = *(const short8*)&Bs[wn * 32 + n * 16 + l15][l4 * 8];
            #pragma unroll
            for (int m = 0; m < 4; ++m)
                #pragma unroll
                for (int n = 0; n < 2; ++n)
                    acc[m * 2 + n] = mfma16(af[m], bf[n], acc[m * 2 + n]);
        } else {
            short8 af[2], bf[4];
            #pragma unroll
            for (int mj = 0; mj < 2; ++mj)
                af[mj] = *(const short8*)&Bs[wn * 32 + mj * 16 + l15][l4 * 8];
            #pragma unroll
            for (int ni = 0; ni < 4; ++ni)
                bf[ni] = *(const short8*)&As[wm * 64 + ni * 16 + l15][l4 * 8];
            #pragma unroll
            for (int mj = 0; mj < 2; ++mj)
                #pragma unroll
                for (int ni = 0; ni < 4; ++ni)
                    acc[mj * 4 + ni] = mfma16(af[mj], bf[ni], acc[mj * 4 + ni]);
        }
    }

    if (which < 2) {
        u16* dst = (which == 0) ? qb : kb;
        const int h = (j0 & 511) >> 6;
        #pragma unroll
        for (int m = 0; m < 4; ++m)
            #pragma unroll
            for (int n = 0; n < 2; ++n) {
                int d = wn * 32 + n * 16 + l15;
                #pragma unroll
                for (int r = 0; r < 4; ++r) {
                    int tok = i0 + wm * 64 + m * 16 + l4 * 4 + r;
                    dst[(((size_t)(b * HEADS + h)) * NSEQ + (tok & 1023)) * DHEAD + d] =
                        f2bf(acc[m * 2 + n][r]);
                }
            }
    } else {
        const int h = (j0 - 1024) >> 6;
        #pragma unroll
        for (int mj = 0; mj < 2; ++mj)
            #pragma unroll
            for (int ni = 0; ni < 4; ++ni) {
                int tok = i0 + wm * 64 + ni * 16 + l15;
                #pragma unroll
                for (int r = 0; r < 4; ++r) {
                    int d = wn * 32 + mj * 16 + l4 * 4 + r;
                    vT[(((size_t)(b * HEADS + h)) * DHEAD + d) * NSEQ + (tok & 1023)] =
                        f2bf(acc[mj * 4 + ni][r]);
                }
            }
    }
}

// ---------------------------------------------------------------------------
// Flash attention (exact R7): swapped-QK^T, KVBLK=64, log2-domain softmax +
// defer-max, coalesced spd->LDS bounce (stride-65), 128 i-rows, 4 waves.
// ---------------------------------------------------------------------------
__global__ __launch_bounds__(256) void attn_mfma(const u16* __restrict__ qb,
                                                 const u16* __restrict__ kb,
                                                 const u16* __restrict__ vT,
                                                 const float* __restrict__ spd,
                                                 const float* __restrict__ head_keep,
                                                 u16* __restrict__ ab) {
    __shared__ u16 Qs[128][72];
    __shared__ u16 Ks[64][72];
    __shared__ u16 Vs[64][72];
    __shared__ float Ss[128][65];

    const int t = threadIdx.x, lane = t & 63, w = t >> 6;
    const int hi = lane >> 5, li = lane & 31;
    const int bh = blockIdx.y, b = bh >> 3, h = bh & 7;
    const int i0 = blockIdx.x * 128;

    const u16* qh = qb + (size_t)bh * NSEQ * DHEAD;
    const u16* kh = kb + (size_t)bh * NSEQ * DHEAD;
    const u16* vh = vT + (size_t)bh * DHEAD * NSEQ;
    const float* sp = spd + (size_t)bh * NSEQ * NSEQ;

    #pragma unroll
    for (int rep = 0; rep < 4; ++rep) {
        int row = rep * 32 + (t >> 3), c8 = (t & 7) * 8;
        *(short8*)&Qs[row][c8] = *(const short8*)&qh[(size_t)(i0 + row) * DHEAD + c8];
    }

    float m_s = -1e30f, l_s = 0.f;
    f32x16 o0 = {}, o1 = {};
    #pragma unroll
    for (int r = 0; r < 16; ++r) { o0[r] = 0.f; o1[r] = 0.f; }

    short8 rk[2], rv[2];
    float4 rs[8];
    {
        int row = t >> 3, c8 = (t & 7) * 8;
        #pragma unroll
        for (int rep = 0; rep < 2; ++rep) {
            rk[rep] = *(const short8*)&kh[(size_t)(rep * 32 + row) * DHEAD + c8];
            rv[rep] = *(const short8*)&vh[(size_t)(rep * 32 + row) * NSEQ + c8];
        }
        #pragma unroll
        for (int rep = 0; rep < 8; ++rep) {
            int rrow = rep * 16 + (t >> 4), c = (t & 15) * 4;
            rs[rep] = *(const float4*)&sp[(size_t)(i0 + rrow) * NSEQ + c];
        }
    }

    for (int jt = 0; jt < 16; ++jt) {
        __syncthreads();
        {
            int row = t >> 3, c8 = (t & 7) * 8;
            #pragma unroll
            for (int rep = 0; rep < 2; ++rep) {
                *(short8*)&Ks[rep * 32 + row][c8] = rk[rep];
                *(short8*)&Vs[rep * 32 + row][c8] = rv[rep];
            }
            #pragma unroll
            for (int rep = 0; rep < 8; ++rep) {
                int rrow = rep * 16 + (t >> 4), c = (t & 15) * 4;
                Ss[rrow][c + 0] = rs[rep].x * LOG2E;
                Ss[rrow][c + 1] = rs[rep].y * LOG2E;
                Ss[rrow][c + 2] = rs[rep].z * LOG2E;
                Ss[rrow][c + 3] = rs[rep].w * LOG2E;
            }
        }
        __syncthreads();
        if (jt < 15) {
            int j0n = (jt + 1) * 64;
            int row = t >> 3, c8 = (t & 7) * 8;
            #pragma unroll
            for (int rep = 0; rep < 2; ++rep) {
                rk[rep] = *(const short8*)&kh[(size_t)(j0n + rep * 32 + row) * DHEAD + c8];
                rv[rep] = *(const short8*)&vh[(size_t)(rep * 32 + row) * NSEQ + j0n + c8];
            }
            #pragma unroll
            for (int rep = 0; rep < 8; ++rep) {
                int rrow = rep * 16 + (t >> 4), c = (t & 15) * 4;
                rs[rep] = *(const float4*)&sp[(size_t)(i0 + rrow) * NSEQ + j0n + c];
            }
        }

        f32x16 s2[2];
        #pragma unroll
        for (int kg = 0; kg < 2; ++kg) {
            #pragma unroll
            for (int r = 0; r < 16; ++r) s2[kg][r] = 0.f;
            #pragma unroll
            for (int ds = 0; ds < 4; ++ds) {
                short8 ak = *(const short8*)&Ks[kg * 32 + li][ds * 16 + hi * 8];
                short8 bq = *(const short8*)&Qs[w * 32 + li][ds * 16 + hi * 8];
                s2[kg] = mfma32(ak, bq, s2[kg]);
            }
        }

        float p2[32];
        #pragma unroll
        for (int kg = 0; kg < 2; ++kg)
            #pragma unroll
            for (int r = 0; r < 16; ++r) {
                int key = kg * 32 + (r & 3) + 8 * (r >> 2) + 4 * hi;
                p2[kg * 16 + r] = fmaf(s2[kg][r], SCALE * LOG2E, Ss[w * 32 + li][key]);
            }
        float m16[16];
        #pragma unroll
        for (int r = 0; r < 16; ++r) m16[r] = fmaxf(p2[r], p2[r + 16]);
        float m8v[8];
        #pragma unroll
        for (int r = 0; r < 8; ++r) m8v[r] = fmaxf(m16[r], m16[r + 8]);
        float m4v[4];
        #pragma unroll
        for (int r = 0; r < 4; ++r) m4v[r] = fmaxf(m8v[r], m8v[r + 4]);
        float pmax = fmaxf(fmaxf(m4v[0], m4v[1]), fmaxf(m4v[2], m4v[3]));
        pmax = fmaxf(pmax, __shfl_xor(pmax, 32));

        if (!__all(pmax <= m_s + 12.0f)) {
            float mnew = fmaxf(m_s, pmax);
            float fac = exp2_fast(m_s - mnew);
            m_s = mnew;
            l_s *= fac;
            #pragma unroll
            for (int r = 0; r < 16; ++r) {
                int ip = (r & 3) + 8 * (r >> 2) + 4 * hi;
                float fr = __shfl(fac, ip);
                o0[r] *= fr; o1[r] *= fr;
            }
        }

        float p[32];
        float sa0 = 0.f, sa1 = 0.f, sa2 = 0.f, sa3 = 0.f;
        #pragma unroll
        for (int r = 0; r < 32; r += 4) {
            p[r + 0] = exp2_fast(p2[r + 0] - m_s); sa0 += p[r + 0];
            p[r + 1] = exp2_fast(p2[r + 1] - m_s); sa1 += p[r + 1];
            p[r + 2] = exp2_fast(p2[r + 2] - m_s); sa2 += p[r + 2];
            p[r + 3] = exp2_fast(p2[r + 3] - m_s); sa3 += p[r + 3];
        }
        float rsum = (sa0 + sa1) + (sa2 + sa3);
        rsum += __shfl_xor(rsum, 32);
        l_s += rsum;

        short8 pf[4];
        #pragma unroll
        for (int ks = 0; ks < 4; ++ks) {
            int rb = (ks >> 1) * 16 + (ks & 1) * 8;
            u32 a0 = pk2(p[rb + 0], p[rb + 1]);
            u32 a1 = pk2(p[rb + 2], p[rb + 3]);
            u32 a2 = pk2(p[rb + 4], p[rb + 5]);
            u32 a3 = pk2(p[rb + 6], p[rb + 7]);
            u32 x0 = (u32)__shfl_xor((int)a0, 32);
            u32 x1 = (u32)__shfl_xor((int)a1, 32);
            u32 x2 = (u32)__shfl_xor((int)a2, 32);
            u32 x3 = (u32)__shfl_xor((int)a3, 32);
            union { u32 u[4]; short8 v; } c4;
            c4.u[0] = hi ? x2 : a0;
            c4.u[1] = hi ? x3 : a1;
            c4.u[2] = hi ? a2 : x0;
            c4.u[3] = hi ? a3 : x1;
            pf[ks] = c4.v;
        }

        #pragma unroll
        for (int ks = 0; ks < 4; ++ks) {
            short8 v0f = *(const short8*)&Vs[li][ks * 16 + hi * 8];
            short8 v1f = *(const short8*)&Vs[32 + li][ks * 16 + hi * 8];
            o0 = mfma32(pf[ks], v0f, o0);
            o1 = mfma32(pf[ks], v1f, o1);
        }
    }

    float ksum = 0.f;
    #pragma unroll
    for (int i = 0; i < HEADS; ++i) ksum += head_keep[i];
    const float hscale = head_keep[h] * (float)HEADS / ksum;
    const float inv = hscale / l_s;
    #pragma unroll
    for (int r = 0; r < 16; ++r) {
        int ip = (r & 3) + 8 * (r >> 2) + 4 * hi;
        float invr = __shfl(inv, ip);
        int tok = i0 + w * 32 + ip;
        size_t base = ((size_t)(b * NSEQ) + tok) * 512 + h * DHEAD;
        ab[base + li]      = f2bf(o0[r] * invr);
        ab[base + 32 + li] = f2bf(o1[r] * invr);
    }
}

// ---------------------------------------------------------------------------
// GEMM out (exact R7): BM=64 x BN=64, BK=32, grid 8x64 = 512 blocks.
// ---------------------------------------------------------------------------
__global__ __launch_bounds__(256) void gemm_out_mfma(const u16* __restrict__ abuf,
                                                     const u16* __restrict__ wT,
                                                     const float* __restrict__ bias,
                                                     float* __restrict__ out) {
    __shared__ u16 As[64][40];
    __shared__ u16 Bs[64][40];
    const int t = threadIdx.x, lane = t & 63, w = t >> 6;
    const int wm = w >> 1, wn = w & 1;
    const int l15 = lane & 15, l4 = lane >> 4;
    const int j0 = blockIdx.x * 64, i0 = blockIdx.y * 64;

    f32x4 acc[2][2];
    #pragma unroll
    for (int m = 0; m < 2; ++m)
        #pragma unroll
        for (int n = 0; n < 2; ++n) acc[m][n] = (f32x4){0.f, 0.f, 0.f, 0.f};

    short8 rav, rbv;
    {
        int row = t >> 2, c8 = (t & 3) * 8;
        rav = *(const short8*)&abuf[(size_t)(i0 + row) * 512 + c8];
        rbv = *(const short8*)&wT[(size_t)(j0 + row) * 512 + c8];
    }

    for (int kt = 0; kt < 16; ++kt) {
        __syncthreads();
        {
            int row = t >> 2, c8 = (t & 3) * 8;
            *(short8*)&As[row][c8] = rav;
            *(short8*)&Bs[row][c8] = rbv;
        }
        __syncthreads();
        if (kt < 15) {
            int k0 = (kt + 1) * 32;
            int row = t >> 2, c8 = (t & 3) * 8;
            rav = *(const short8*)&abuf[(size_t)(i0 + row) * 512 + k0 + c8];
            rbv = *(const short8*)&wT[(size_t)(j0 + row) * 512 + k0 + c8];
        }
        short8 af[2], bf[2];
        #pragma unroll
        for (int m = 0; m < 2; ++m)
            af[m] = *(const short8*)&As[wm * 32 + m * 16 + l15][l4 * 8];
        #pragma unroll
        for (int n = 0; n < 2; ++n)
            bf[n] = *(const short8*)&Bs[wn * 32 + n * 16 + l15][l4 * 8];
        #pragma unroll
        for (int m = 0; m < 2; ++m)
            #pragma unroll
            for (int n = 0; n < 2; ++n)
                acc[m][n] = mfma16(af[m], bf[n], acc[m][n]);
    }

    #pragma unroll
    for (int m = 0; m < 2; ++m)
        #pragma unroll
        for (int n = 0; n < 2; ++n) {
            int col = j0 + wn * 32 + n * 16 + l15;
            float bb = bias[col];
            #pragma unroll
            for (int r = 0; r < 4; ++r) {
                int row = i0 + wm * 32 + m * 16 + l4 * 4 + r;
                out[(size_t)row * 512 + col] = acc[m][n][r] + bb;
            }
        }
}

extern "C" void kernel_launch(void* const* d_in, const int* in_sizes, int n_in,
                              void* d_out, int out_size, void* d_ws, size_t ws_size,
                              hipStream_t stream) {
    const float* x         = (const float*)d_in[0];
    const float* spd       = (const float*)d_in[1];
    const float* head_keep = (const float*)d_in[2];
    const float* w_qkv     = (const float*)d_in[3];
    const float* w_out     = (const float*)d_in[4];
    const float* b_out     = (const float*)d_in[5];
    float* out = (float*)d_out;

    char* ws = (char*)d_ws;
    u16* wqkvT  = (u16*)(ws + (4u << 20));          // 1536*512
    u16* woutT  = (u16*)(ws + (4u << 20) + 1572864);// 512*512
    u16* qb     = (u16*)(ws + (6u << 20));          // 32*1024*64
    u16* kb     = (u16*)(ws + (10u << 20));
    u16* vT     = (u16*)(ws + (14u << 20));
    u16* ab     = (u16*)(ws + (18u << 20));         // 4096*512

    prep<<<256, 256, 0, stream>>>(w_qkv, w_out, wqkvT, woutT);
    gemm_qkv_mfma<<<dim3(24, 32), 256, 0, stream>>>(x, wqkvT, qb, kb, vT);
    attn_mfma<<<dim3(8, 32), 256, 0, stream>>>(qb, kb, vT, spd, head_keep, ab);
    gemm_out_mfma<<<dim3(8, 64), 256, 0, stream>>>(ab, woutT, b_out, out);
}

// Round 12
// 66.353 us; speedup vs baseline: 1.0863x; 1.0863x over previous
//
#include <hip/hip_runtime.h>
#include <math.h>

#define NSEQ   1024
#define HEADS  8
#define DHEAD  64
#define SCALE  0.125f
#define LOG2E  1.4426950408889634f

typedef unsigned int u32;
typedef unsigned short u16;
typedef short short8 __attribute__((ext_vector_type(8)));   // 8 bf16 (4 VGPRs)
typedef __bf16 bf16x2 __attribute__((ext_vector_type(2)));
typedef __bf16 bf16x8 __attribute__((ext_vector_type(8)));
typedef float f32x4  __attribute__((ext_vector_type(4)));
typedef float f32x16 __attribute__((ext_vector_type(16)));

__device__ __forceinline__ u16 f2bf(float f) {
    __bf16 h = (__bf16)f;
    return __builtin_bit_cast(u16, h);
}
__device__ __forceinline__ u32 pk2(float lo, float hi) {
    bf16x2 v; v[0] = (__bf16)lo; v[1] = (__bf16)hi;
    return __builtin_bit_cast(u32, v);
}
// no inline-asm exp (R6 lesson: unscheduled TRANS hazard -> nondeterminism)
__device__ __forceinline__ float exp2_fast(float x) {
#if __has_builtin(__builtin_amdgcn_exp2f)
    return __builtin_amdgcn_exp2f(x);
#else
    return exp2f(x);
#endif
}
__device__ __forceinline__ f32x4 mfma16(short8 a, short8 b, f32x4 c) {
    return __builtin_amdgcn_mfma_f32_16x16x32_bf16(a, b, c, 0, 0, 0);
}
__device__ __forceinline__ f32x16 mfma32(short8 a, short8 b, f32x16 c) {
    return __builtin_amdgcn_mfma_f32_32x32x16_bf16(a, b, c, 0, 0, 0);
}

// ---------------------------------------------------------------------------
// prep (R7-exact): x->bf16 convert + both weight transpose-converts.
// blocks [0,1024): conv x; [1024,1216): w_qkv^T; [1216,1280): w_out^T.
// ---------------------------------------------------------------------------
__global__ __launch_bounds__(256) void prep(const float* __restrict__ x,
                                            const float* __restrict__ wqkv,
                                            const float* __restrict__ wout,
                                            u16* __restrict__ x_bf,
                                            u16* __restrict__ wqkvT,
                                            u16* __restrict__ woutT) {
    __shared__ float T[64][65];
    const int t = threadIdx.x;
    const int bb = blockIdx.x;
    if (bb < 1024) {
        int i = (bb * 256 + t) * 8;
        float4 a = *(const float4*)&x[i];
        float4 b = *(const float4*)&x[i + 4];
        bf16x8 v;
        v[0] = (__bf16)a.x; v[1] = (__bf16)a.y; v[2] = (__bf16)a.z; v[3] = (__bf16)a.w;
        v[4] = (__bf16)b.x; v[5] = (__bf16)b.y; v[6] = (__bf16)b.z; v[7] = (__bf16)b.w;
        *(short8*)&x_bf[i] = __builtin_bit_cast(short8, v);
        return;
    }
    const float* in; u16* outp; int K, N, n0, k0;
    if (bb < 1216) {
        int bid = bb - 1024;
        in = wqkv; outp = wqkvT; K = 512; N = 1536;
        n0 = (bid % 24) * 64; k0 = (bid / 24) * 64;
    } else {
        int bid = bb - 1216;
        in = wout; outp = woutT; K = 512; N = 512;
        n0 = (bid % 8) * 64; k0 = (bid / 8) * 64;
    }
    #pragma unroll
    for (int rep = 0; rep < 4; ++rep) {
        int r = rep * 16 + (t >> 4), c = (t & 15) * 4;
        float4 v = *(const float4*)&in[(size_t)(k0 + r) * N + n0 + c];
        T[r][c + 0] = v.x; T[r][c + 1] = v.y; T[r][c + 2] = v.z; T[r][c + 3] = v.w;
    }
    __syncthreads();
    const int nl = t >> 2, kb = (t & 3) * 16;
    bf16x8 s0, s1;
    #pragma unroll
    for (int e = 0; e < 8; ++e) s0[e] = (__bf16)T[kb + e][nl];
    #pragma unroll
    for (int e = 0; e < 8; ++e) s1[e] = (__bf16)T[kb + 8 + e][nl];
    *(short8*)&outp[(size_t)(n0 + nl) * K + k0 + kb]     = __builtin_bit_cast(short8, s0);
    *(short8*)&outp[(size_t)(n0 + nl) * K + k0 + kb + 8] = __builtin_bit_cast(short8, s1);
}

// ---------------------------------------------------------------------------
// GEMM qkv (R7-exact): C = x_bf[4096,512] @ w (wT[1536][512] bf16).
// BM=128 x BN=64, BK=32, grid 24x32.  v path writes C^T -> vT[b,h,d,n].
// ---------------------------------------------------------------------------
__global__ __launch_bounds__(256) void gemm_qkv_mfma(const u16* __restrict__ xb,
                                                     const u16* __restrict__ wT,
                                                     u16* __restrict__ qb,
                                                     u16* __restrict__ kb,
                                                     u16* __restrict__ vT) {
    __shared__ u16 As[128][40];
    __shared__ u16 Bs[64][40];
    const int t = threadIdx.x, lane = t & 63, w = t >> 6;
    const int wm = w >> 1, wn = w & 1;
    const int l15 = lane & 15, l4 = lane >> 4;
    const int j0 = blockIdx.x * 64, i0 = blockIdx.y * 128;
    const int which = j0 / 512;           // 0=q 1=k 2=v (uniform per block)
    const int b = i0 >> 10;

    f32x4 acc[8];
    #pragma unroll
    for (int i = 0; i < 8; ++i) acc[i] = (f32x4){0.f, 0.f, 0.f, 0.f};

    short8 ra[2], rbv;
    #pragma unroll
    for (int rep = 0; rep < 2; ++rep) {
        int row = rep * 64 + (t >> 2), c8 = (t & 3) * 8;
        ra[rep] = *(const short8*)&xb[(size_t)(i0 + row) * 512 + c8];
    }
    {
        int row = t >> 2, c8 = (t & 3) * 8;
        rbv = *(const short8*)&wT[(size_t)(j0 + row) * 512 + c8];
    }

    for (int kt = 0; kt < 16; ++kt) {
        __syncthreads();
        #pragma unroll
        for (int rep = 0; rep < 2; ++rep) {
            int row = rep * 64 + (t >> 2), c8 = (t & 3) * 8;
            *(short8*)&As[row][c8] = ra[rep];
        }
        {
            int row = t >> 2, c8 = (t & 3) * 8;
            *(short8*)&Bs[row][c8] = rbv;
        }
        __syncthreads();
        if (kt < 15) {
            int k0 = (kt + 1) * 32;
            #pragma unroll
            for (int rep = 0; rep < 2; ++rep) {
                int row = rep * 64 + (t >> 2), c8 = (t & 3) * 8;
                ra[rep] = *(const short8*)&xb[(size_t)(i0 + row) * 512 + k0 + c8];
            }
            int row = t >> 2, c8 = (t & 3) * 8;
            rbv = *(const short8*)&wT[(size_t)(j0 + row) * 512 + k0 + c8];
        }
        if (which < 2) {
            short8 af[4], bf[2];
            #pragma unroll
            for (int m = 0; m < 4; ++m)
                af[m] = *(const short8*)&As[wm * 64 + m * 16 + l15][l4 * 8];
            #pragma unroll
            for (int n = 0; n < 2; ++n)
                bf[n] = *(const short8*)&Bs[wn * 32 + n * 16 + l15][l4 * 8];
            #pragma unroll
            for (int m = 0; m < 4; ++m)
                #pragma unroll
                for (int n = 0; n < 2; ++n)
                    acc[m * 2 + n] = mfma16(af[m], bf[n], acc[m * 2 + n]);
        } else {
            short8 af[2], bf[4];
            #pragma unroll
            for (int mj = 0; mj < 2; ++mj)
                af[mj] = *(const short8*)&Bs[wn * 32 + mj * 16 + l15][l4 * 8];
            #pragma unroll
            for (int ni = 0; ni < 4; ++ni)
                bf[ni] = *(const short8*)&As[wm * 64 + ni * 16 + l15][l4 * 8];
            #pragma unroll
            for (int mj = 0; mj < 2; ++mj)
                #pragma unroll
                for (int ni = 0; ni < 4; ++ni)
                    acc[mj * 4 + ni] = mfma16(af[mj], bf[ni], acc[mj * 4 + ni]);
        }
    }

    if (which < 2) {
        u16* dst = (which == 0) ? qb : kb;
        const int h = (j0 & 511) >> 6;
        #pragma unroll
        for (int m = 0; m < 4; ++m)
            #pragma unroll
            for (int n = 0; n < 2; ++n) {
                int d = wn * 32 + n * 16 + l15;
                #pragma unroll
                for (int r = 0; r < 4; ++r) {
                    int tok = i0 + wm * 64 + m * 16 + l4 * 4 + r;
                    dst[(((size_t)(b * HEADS + h)) * NSEQ + (tok & 1023)) * DHEAD + d] =
                        f2bf(acc[m * 2 + n][r]);
                }
            }
    } else {
        const int h = (j0 - 1024) >> 6;
        #pragma unroll
        for (int mj = 0; mj < 2; ++mj)
            #pragma unroll
            for (int ni = 0; ni < 4; ++ni) {
                int tok = i0 + wm * 64 + ni * 16 + l15;
                #pragma unroll
                for (int r = 0; r < 4; ++r) {
                    int d = wn * 32 + mj * 16 + l4 * 4 + r;
                    vT[(((size_t)(b * HEADS + h)) * DHEAD + d) * NSEQ + (tok & 1023)] =
                        f2bf(acc[mj * 4 + ni][r]);
                }
            }
    }
}

// ---------------------------------------------------------------------------
// Flash attention v4: R7 dataflow + double-buffered LDS stages (K/V/spd) ->
// ONE barrier per jt, loads issued a full iteration ahead (2 compute phases
// of latency cover).  Access patterns / tiles / softmax identical to R7.
// ---------------------------------------------------------------------------
__global__ __launch_bounds__(256) void attn_mfma(const u16* __restrict__ qb,
                                                 const u16* __restrict__ kb,
                                                 const u16* __restrict__ vT,
                                                 const float* __restrict__ spd,
                                                 const float* __restrict__ head_keep,
                                                 u16* __restrict__ ab) {
    __shared__ u16 Qs[128][72];
    __shared__ u16 Kd[2][64][72];
    __shared__ u16 Vd[2][64][72];
    __shared__ float Sd[2][128][65];

    const int t = threadIdx.x, lane = t & 63, w = t >> 6;
    const int hi = lane >> 5, li = lane & 31;
    const int bh = blockIdx.y, b = bh >> 3, h = bh & 7;
    const int i0 = blockIdx.x * 128;

    const u16* qh = qb + (size_t)bh * NSEQ * DHEAD;
    const u16* kh = kb + (size_t)bh * NSEQ * DHEAD;
    const u16* vh = vT + (size_t)bh * DHEAD * NSEQ;
    const float* sp = spd + (size_t)bh * NSEQ * NSEQ;

    // Q tile [128][64]
    #pragma unroll
    for (int rep = 0; rep < 4; ++rep) {
        int row = rep * 32 + (t >> 3), c8 = (t & 7) * 8;
        *(short8*)&Qs[row][c8] = *(const short8*)&qh[(size_t)(i0 + row) * DHEAD + c8];
    }

    const int krow = t >> 3, kc8 = (t & 7) * 8;
    const int srow = t >> 4, sc = (t & 15) * 4;

    short8 rk[2], rv[2];
    float4 rs[8];
    // tile 0 load + stage into buf0
    #pragma unroll
    for (int rep = 0; rep < 2; ++rep) {
        rk[rep] = *(const short8*)&kh[(size_t)(rep * 32 + krow) * DHEAD + kc8];
        rv[rep] = *(const short8*)&vh[(size_t)(rep * 32 + krow) * NSEQ + kc8];
    }
    #pragma unroll
    for (int rep = 0; rep < 8; ++rep)
        rs[rep] = *(const float4*)&sp[(size_t)(i0 + rep * 16 + srow) * NSEQ + sc];
    #pragma unroll
    for (int rep = 0; rep < 2; ++rep) {
        *(short8*)&Kd[0][rep * 32 + krow][kc8] = rk[rep];
        *(short8*)&Vd[0][rep * 32 + krow][kc8] = rv[rep];
    }
    #pragma unroll
    for (int rep = 0; rep < 8; ++rep) {
        int rrow = rep * 16 + srow;
        Sd[0][rrow][sc + 0] = rs[rep].x * LOG2E;
        Sd[0][rrow][sc + 1] = rs[rep].y * LOG2E;
        Sd[0][rrow][sc + 2] = rs[rep].z * LOG2E;
        Sd[0][rrow][sc + 3] = rs[rep].w * LOG2E;
    }
    // issue tile-1 loads (fly across the barrier and iteration-0 compute)
    #pragma unroll
    for (int rep = 0; rep < 2; ++rep) {
        rk[rep] = *(const short8*)&kh[(size_t)(64 + rep * 32 + krow) * DHEAD + kc8];
        rv[rep] = *(const short8*)&vh[(size_t)(rep * 32 + krow) * NSEQ + 64 + kc8];
    }
    #pragma unroll
    for (int rep = 0; rep < 8; ++rep)
        rs[rep] = *(const float4*)&sp[(size_t)(i0 + rep * 16 + srow) * NSEQ + 64 + sc];
    __syncthreads();

    float m_s = -1e30f, l_s = 0.f;
    f32x16 o0 = {}, o1 = {};
    #pragma unroll
    for (int r = 0; r < 16; ++r) { o0[r] = 0.f; o1[r] = 0.f; }

    for (int jt = 0; jt < 16; ++jt) {
        const int cur = jt & 1;

        // ---- compute tile jt from buf[cur] ----
        f32x16 s2[2];
        #pragma unroll
        for (int kg = 0; kg < 2; ++kg) {
            #pragma unroll
            for (int r = 0; r < 16; ++r) s2[kg][r] = 0.f;
            #pragma unroll
            for (int ds = 0; ds < 4; ++ds) {
                short8 ak = *(const short8*)&Kd[cur][kg * 32 + li][ds * 16 + hi * 8];
                short8 bq = *(const short8*)&Qs[w * 32 + li][ds * 16 + hi * 8];
                s2[kg] = mfma32(ak, bq, s2[kg]);
            }
        }

        float p2[32];
        #pragma unroll
        for (int kg = 0; kg < 2; ++kg)
            #pragma unroll
            for (int r = 0; r < 16; ++r) {
                int key = kg * 32 + (r & 3) + 8 * (r >> 2) + 4 * hi;
                p2[kg * 16 + r] = fmaf(s2[kg][r], SCALE * LOG2E, Sd[cur][w * 32 + li][key]);
            }
        float m16[16];
        #pragma unroll
        for (int r = 0; r < 16; ++r) m16[r] = fmaxf(p2[r], p2[r + 16]);
        float m8v[8];
        #pragma unroll
        for (int r = 0; r < 8; ++r) m8v[r] = fmaxf(m16[r], m16[r + 8]);
        float m4v[4];
        #pragma unroll
        for (int r = 0; r < 4; ++r) m4v[r] = fmaxf(m8v[r], m8v[r + 4]);
        float pmax = fmaxf(fmaxf(m4v[0], m4v[1]), fmaxf(m4v[2], m4v[3]));
        pmax = fmaxf(pmax, __shfl_xor(pmax, 32));

        if (!__all(pmax <= m_s + 12.0f)) {
            float mnew = fmaxf(m_s, pmax);
            float fac = exp2_fast(m_s - mnew);
            m_s = mnew;
            l_s *= fac;
            #pragma unroll
            for (int r = 0; r < 16; ++r) {
                int ip = (r & 3) + 8 * (r >> 2) + 4 * hi;
                float fr = __shfl(fac, ip);
                o0[r] *= fr; o1[r] *= fr;
            }
        }

        float p[32];
        float sa0 = 0.f, sa1 = 0.f, sa2 = 0.f, sa3 = 0.f;
        #pragma unroll
        for (int r = 0; r < 32; r += 4) {
            p[r + 0] = exp2_fast(p2[r + 0] - m_s); sa0 += p[r + 0];
            p[r + 1] = exp2_fast(p2[r + 1] - m_s); sa1 += p[r + 1];
            p[r + 2] = exp2_fast(p2[r + 2] - m_s); sa2 += p[r + 2];
            p[r + 3] = exp2_fast(p2[r + 3] - m_s); sa3 += p[r + 3];
        }
        float rsum = (sa0 + sa1) + (sa2 + sa3);
        rsum += __shfl_xor(rsum, 32);
        l_s += rsum;

        short8 pf[4];
        #pragma unroll
        for (int ks = 0; ks < 4; ++ks) {
            int rb = (ks >> 1) * 16 + (ks & 1) * 8;
            u32 a0 = pk2(p[rb + 0], p[rb + 1]);
            u32 a1 = pk2(p[rb + 2], p[rb + 3]);
            u32 a2 = pk2(p[rb + 4], p[rb + 5]);
            u32 a3 = pk2(p[rb + 6], p[rb + 7]);
            u32 x0 = (u32)__shfl_xor((int)a0, 32);
            u32 x1 = (u32)__shfl_xor((int)a1, 32);
            u32 x2 = (u32)__shfl_xor((int)a2, 32);
            u32 x3 = (u32)__shfl_xor((int)a3, 32);
            union { u32 u[4]; short8 v; } c4;
            c4.u[0] = hi ? x2 : a0;
            c4.u[1] = hi ? x3 : a1;
            c4.u[2] = hi ? a2 : x0;
            c4.u[3] = hi ? a3 : x1;
            pf[ks] = c4.v;
        }

        #pragma unroll
        for (int ks = 0; ks < 4; ++ks) {
            short8 v0f = *(const short8*)&Vd[cur][li][ks * 16 + hi * 8];
            short8 v1f = *(const short8*)&Vd[cur][32 + li][ks * 16 + hi * 8];
            o0 = mfma32(pf[ks], v0f, o0);
            o1 = mfma32(pf[ks], v1f, o1);
        }

        // ---- stage tile jt+1 into buf[cur^1]; issue tile jt+2 loads ----
        if (jt < 15) {
            const int nxt = cur ^ 1;
            #pragma unroll
            for (int rep = 0; rep < 2; ++rep) {
                *(short8*)&Kd[nxt][rep * 32 + krow][kc8] = rk[rep];
                *(short8*)&Vd[nxt][rep * 32 + krow][kc8] = rv[rep];
            }
            #pragma unroll
            for (int rep = 0; rep < 8; ++rep) {
                int rrow = rep * 16 + srow;
                Sd[nxt][rrow][sc + 0] = rs[rep].x * LOG2E;
                Sd[nxt][rrow][sc + 1] = rs[rep].y * LOG2E;
                Sd[nxt][rrow][sc + 2] = rs[rep].z * LOG2E;
                Sd[nxt][rrow][sc + 3] = rs[rep].w * LOG2E;
            }
            if (jt < 14) {
                int j0n = (jt + 2) * 64;
                #pragma unroll
                for (int rep = 0; rep < 2; ++rep) {
                    rk[rep] = *(const short8*)&kh[(size_t)(j0n + rep * 32 + krow) * DHEAD + kc8];
                    rv[rep] = *(const short8*)&vh[(size_t)(rep * 32 + krow) * NSEQ + j0n + kc8];
                }
                #pragma unroll
                for (int rep = 0; rep < 8; ++rep)
                    rs[rep] = *(const float4*)&sp[(size_t)(i0 + rep * 16 + srow) * NSEQ + j0n + sc];
            }
            __syncthreads();
        }
    }

    // epilogue
    float ksum = 0.f;
    #pragma unroll
    for (int i = 0; i < HEADS; ++i) ksum += head_keep[i];
    const float hscale = head_keep[h] * (float)HEADS / ksum;
    const float inv = hscale / l_s;
    #pragma unroll
    for (int r = 0; r < 16; ++r) {
        int ip = (r & 3) + 8 * (r >> 2) + 4 * hi;
        float invr = __shfl(inv, ip);
        int tok = i0 + w * 32 + ip;
        size_t base = ((size_t)(b * NSEQ) + tok) * 512 + h * DHEAD;
        ab[base + li]      = f2bf(o0[r] * invr);
        ab[base + 32 + li] = f2bf(o1[r] * invr);
    }
}

// ---------------------------------------------------------------------------
// GEMM out (R7-exact): BM=64 x BN=64, BK=32, grid 8x64 = 512 blocks.
// ---------------------------------------------------------------------------
__global__ __launch_bounds__(256) void gemm_out_mfma(const u16* __restrict__ abuf,
                                                     const u16* __restrict__ wT,
                                                     const float* __restrict__ bias,
                                                     float* __restrict__ out) {
    __shared__ u16 As[64][40];
    __shared__ u16 Bs[64][40];
    const int t = threadIdx.x, lane = t & 63, w = t >> 6;
    const int wm = w >> 1, wn = w & 1;
    const int l15 = lane & 15, l4 = lane >> 4;
    const int j0 = blockIdx.x * 64, i0 = blockIdx.y * 64;

    f32x4 acc[2][2];
    #pragma unroll
    for (int m = 0; m < 2; ++m)
        #pragma unroll
        for (int n = 0; n < 2; ++n) acc[m][n] = (f32x4){0.f, 0.f, 0.f, 0.f};

    short8 rav, rbv;
    {
        int row = t >> 2, c8 = (t & 3) * 8;
        rav = *(const short8*)&abuf[(size_t)(i0 + row) * 512 + c8];
        rbv = *(const short8*)&wT[(size_t)(j0 + row) * 512 + c8];
    }

    for (int kt = 0; kt < 16; ++kt) {
        __syncthreads();
        {
            int row = t >> 2, c8 = (t & 3) * 8;
            *(short8*)&As[row][c8] = rav;
            *(short8*)&Bs[row][c8] = rbv;
        }
        __syncthreads();
        if (kt < 15) {
            int k0 = (kt + 1) * 32;
            int row = t >> 2, c8 = (t & 3) * 8;
            rav = *(const short8*)&abuf[(size_t)(i0 + row) * 512 + k0 + c8];
            rbv = *(const short8*)&wT[(size_t)(j0 + row) * 512 + k0 + c8];
        }
        short8 af[2], bf[2];
        #pragma unroll
        for (int m = 0; m < 2; ++m)
            af[m] = *(const short8*)&As[wm * 32 + m * 16 + l15][l4 * 8];
        #pragma unroll
        for (int n = 0; n < 2; ++n)
            bf[n] = *(const short8*)&Bs[wn * 32 + n * 16 + l15][l4 * 8];
        #pragma unroll
        for (int m = 0; m < 2; ++m)
            #pragma unroll
            for (int n = 0; n < 2; ++n)
                acc[m][n] = mfma16(af[m], bf[n], acc[m][n]);
    }

    #pragma unroll
    for (int m = 0; m < 2; ++m)
        #pragma unroll
        for (int n = 0; n < 2; ++n) {
            int col = j0 + wn * 32 + n * 16 + l15;
            float bb = bias[col];
            #pragma unroll
            for (int r = 0; r < 4; ++r) {
                int row = i0 + wm * 32 + m * 16 + l4 * 4 + r;
                out[(size_t)row * 512 + col] = acc[m][n][r] + bb;
            }
        }
}

extern "C" void kernel_launch(void* const* d_in, const int* in_sizes, int n_in,
                              void* d_out, int out_size, void* d_ws, size_t ws_size,
                              hipStream_t stream) {
    const float* x         = (const float*)d_in[0];
    const float* spd       = (const float*)d_in[1];
    const float* head_keep = (const float*)d_in[2];
    const float* w_qkv     = (const float*)d_in[3];
    const float* w_out     = (const float*)d_in[4];
    const float* b_out     = (const float*)d_in[5];
    float* out = (float*)d_out;

    char* ws = (char*)d_ws;
    u16* x_bf   = (u16*)(ws);                       // 4096*512
    u16* wqkvT  = (u16*)(ws + (4u << 20));          // 1536*512
    u16* woutT  = (u16*)(ws + (4u << 20) + 1572864);// 512*512
    u16* qb     = (u16*)(ws + (6u << 20));          // 32*1024*64
    u16* kb     = (u16*)(ws + (10u << 20));
    u16* vT     = (u16*)(ws + (14u << 20));
    u16* ab     = (u16*)(ws + (18u << 20));         // 4096*512

    prep<<<1280, 256, 0, stream>>>(x, w_qkv, w_out, x_bf, wqkvT, woutT);
    gemm_qkv_mfma<<<dim3(24, 32), 256, 0, stream>>>(x_bf, wqkvT, qb, kb, vT);
    attn_mfma<<<dim3(8, 32), 256, 0, stream>>>(qb, kb, vT, spd, head_keep, ab);
    gemm_out_mfma<<<dim3(8, 64), 256, 0, stream>>>(ab, woutT, b_out, out);
}

// Round 13
// 64.763 us; speedup vs baseline: 1.1129x; 1.0246x over previous
//
#include <hip/hip_runtime.h>
#include <math.h>

#define NSEQ   1024
#define HEADS  8
#define DHEAD  64
#define SCALE  0.125f
#define LOG2E  1.4426950408889634f

typedef unsigned int u32;
typedef unsigned short u16;
typedef short short8 __attribute__((ext_vector_type(8)));   // 8 bf16 (4 VGPRs)
typedef __bf16 bf16x2 __attribute__((ext_vector_type(2)));
typedef __bf16 bf16x8 __attribute__((ext_vector_type(8)));
typedef float f32x4  __attribute__((ext_vector_type(4)));
typedef float f32x16 __attribute__((ext_vector_type(16)));

__device__ __forceinline__ u16 f2bf(float f) {
    __bf16 h = (__bf16)f;
    return __builtin_bit_cast(u16, h);
}
__device__ __forceinline__ u32 pk2(float lo, float hi) {
    bf16x2 v; v[0] = (__bf16)lo; v[1] = (__bf16)hi;
    return __builtin_bit_cast(u32, v);
}
// no inline-asm exp (R6 lesson: unscheduled TRANS hazard -> nondeterminism)
__device__ __forceinline__ float exp2_fast(float x) {
#if __has_builtin(__builtin_amdgcn_exp2f)
    return __builtin_amdgcn_exp2f(x);
#else
    return exp2f(x);
#endif
}
__device__ __forceinline__ f32x4 mfma16(short8 a, short8 b, f32x4 c) {
    return __builtin_amdgcn_mfma_f32_16x16x32_bf16(a, b, c, 0, 0, 0);
}
__device__ __forceinline__ f32x16 mfma32(short8 a, short8 b, f32x16 c) {
    return __builtin_amdgcn_mfma_f32_32x32x16_bf16(a, b, c, 0, 0, 0);
}

// ---------------------------------------------------------------------------
// prep (R7-exact): x->bf16 convert + both weight transpose-converts.
// blocks [0,1024): conv x; [1024,1216): w_qkv^T; [1216,1280): w_out^T.
// ---------------------------------------------------------------------------
__global__ __launch_bounds__(256) void prep(const float* __restrict__ x,
                                            const float* __restrict__ wqkv,
                                            const float* __restrict__ wout,
                                            u16* __restrict__ x_bf,
                                            u16* __restrict__ wqkvT,
                                            u16* __restrict__ woutT) {
    __shared__ float T[64][65];
    const int t = threadIdx.x;
    const int bb = blockIdx.x;
    if (bb < 1024) {
        int i = (bb * 256 + t) * 8;
        float4 a = *(const float4*)&x[i];
        float4 b = *(const float4*)&x[i + 4];
        bf16x8 v;
        v[0] = (__bf16)a.x; v[1] = (__bf16)a.y; v[2] = (__bf16)a.z; v[3] = (__bf16)a.w;
        v[4] = (__bf16)b.x; v[5] = (__bf16)b.y; v[6] = (__bf16)b.z; v[7] = (__bf16)b.w;
        *(short8*)&x_bf[i] = __builtin_bit_cast(short8, v);
        return;
    }
    const float* in; u16* outp; int K, N, n0, k0;
    if (bb < 1216) {
        int bid = bb - 1024;
        in = wqkv; outp = wqkvT; K = 512; N = 1536;
        n0 = (bid % 24) * 64; k0 = (bid / 24) * 64;
    } else {
        int bid = bb - 1216;
        in = wout; outp = woutT; K = 512; N = 512;
        n0 = (bid % 8) * 64; k0 = (bid / 8) * 64;
    }
    #pragma unroll
    for (int rep = 0; rep < 4; ++rep) {
        int r = rep * 16 + (t >> 4), c = (t & 15) * 4;
        float4 v = *(const float4*)&in[(size_t)(k0 + r) * N + n0 + c];
        T[r][c + 0] = v.x; T[r][c + 1] = v.y; T[r][c + 2] = v.z; T[r][c + 3] = v.w;
    }
    __syncthreads();
    const int nl = t >> 2, kb = (t & 3) * 16;
    bf16x8 s0, s1;
    #pragma unroll
    for (int e = 0; e < 8; ++e) s0[e] = (__bf16)T[kb + e][nl];
    #pragma unroll
    for (int e = 0; e < 8; ++e) s1[e] = (__bf16)T[kb + 8 + e][nl];
    *(short8*)&outp[(size_t)(n0 + nl) * K + k0 + kb]     = __builtin_bit_cast(short8, s0);
    *(short8*)&outp[(size_t)(n0 + nl) * K + k0 + kb + 8] = __builtin_bit_cast(short8, s1);
}

// ---------------------------------------------------------------------------
// GEMM qkv (R7-exact): C = x_bf[4096,512] @ w (wT[1536][512] bf16).
// BM=128 x BN=64, BK=32, grid 24x32.  v path writes C^T -> vT[b,h,d,n].
// ---------------------------------------------------------------------------
__global__ __launch_bounds__(256) void gemm_qkv_mfma(const u16* __restrict__ xb,
                                                     const u16* __restrict__ wT,
                                                     u16* __restrict__ qb,
                                                     u16* __restrict__ kb,
                                                     u16* __restrict__ vT) {
    __shared__ u16 As[128][40];
    __shared__ u16 Bs[64][40];
    const int t = threadIdx.x, lane = t & 63, w = t >> 6;
    const int wm = w >> 1, wn = w & 1;
    const int l15 = lane & 15, l4 = lane >> 4;
    const int j0 = blockIdx.x * 64, i0 = blockIdx.y * 128;
    const int which = j0 / 512;           // 0=q 1=k 2=v (uniform per block)
    const int b = i0 >> 10;

    f32x4 acc[8];
    #pragma unroll
    for (int i = 0; i < 8; ++i) acc[i] = (f32x4){0.f, 0.f, 0.f, 0.f};

    short8 ra[2], rbv;
    #pragma unroll
    for (int rep = 0; rep < 2; ++rep) {
        int row = rep * 64 + (t >> 2), c8 = (t & 3) * 8;
        ra[rep] = *(const short8*)&xb[(size_t)(i0 + row) * 512 + c8];
    }
    {
        int row = t >> 2, c8 = (t & 3) * 8;
        rbv = *(const short8*)&wT[(size_t)(j0 + row) * 512 + c8];
    }

    for (int kt = 0; kt < 16; ++kt) {
        __syncthreads();
        #pragma unroll
        for (int rep = 0; rep < 2; ++rep) {
            int row = rep * 64 + (t >> 2), c8 = (t & 3) * 8;
            *(short8*)&As[row][c8] = ra[rep];
        }
        {
            int row = t >> 2, c8 = (t & 3) * 8;
            *(short8*)&Bs[row][c8] = rbv;
        }
        __syncthreads();
        if (kt < 15) {
            int k0 = (kt + 1) * 32;
            #pragma unroll
            for (int rep = 0; rep < 2; ++rep) {
                int row = rep * 64 + (t >> 2), c8 = (t & 3) * 8;
                ra[rep] = *(const short8*)&xb[(size_t)(i0 + row) * 512 + k0 + c8];
            }
            int row = t >> 2, c8 = (t & 3) * 8;
            rbv = *(const short8*)&wT[(size_t)(j0 + row) * 512 + k0 + c8];
        }
        if (which < 2) {
            short8 af[4], bf[2];
            #pragma unroll
            for (int m = 0; m < 4; ++m)
                af[m] = *(const short8*)&As[wm * 64 + m * 16 + l15][l4 * 8];
            #pragma unroll
            for (int n = 0; n < 2; ++n)
                bf[n] = *(const short8*)&Bs[wn * 32 + n * 16 + l15][l4 * 8];
            #pragma unroll
            for (int m = 0; m < 4; ++m)
                #pragma unroll
                for (int n = 0; n < 2; ++n)
                    acc[m * 2 + n] = mfma16(af[m], bf[n], acc[m * 2 + n]);
        } else {
            short8 af[2], bf[4];
            #pragma unroll
            for (int mj = 0; mj < 2; ++mj)
                af[mj] = *(const short8*)&Bs[wn * 32 + mj * 16 + l15][l4 * 8];
            #pragma unroll
            for (int ni = 0; ni < 4; ++ni)
                bf[ni] = *(const short8*)&As[wm * 64 + ni * 16 + l15][l4 * 8];
            #pragma unroll
            for (int mj = 0; mj < 2; ++mj)
                #pragma unroll
                for (int ni = 0; ni < 4; ++ni)
                    acc[mj * 4 + ni] = mfma16(af[mj], bf[ni], acc[mj * 4 + ni]);
        }
    }

    if (which < 2) {
        u16* dst = (which == 0) ? qb : kb;
        const int h = (j0 & 511) >> 6;
        #pragma unroll
        for (int m = 0; m < 4; ++m)
            #pragma unroll
            for (int n = 0; n < 2; ++n) {
                int d = wn * 32 + n * 16 + l15;
                #pragma unroll
                for (int r = 0; r < 4; ++r) {
                    int tok = i0 + wm * 64 + m * 16 + l4 * 4 + r;
                    dst[(((size_t)(b * HEADS + h)) * NSEQ + (tok & 1023)) * DHEAD + d] =
                        f2bf(acc[m * 2 + n][r]);
                }
            }
    } else {
        const int h = (j0 - 1024) >> 6;
        #pragma unroll
        for (int mj = 0; mj < 2; ++mj)
            #pragma unroll
            for (int ni = 0; ni < 4; ++ni) {
                int tok = i0 + wm * 64 + ni * 16 + l15;
                #pragma unroll
                for (int r = 0; r < 4; ++r) {
                    int d = wn * 32 + mj * 16 + l4 * 4 + r;
                    vT[(((size_t)(b * HEADS + h)) * DHEAD + d) * NSEQ + (tok & 1023)] =
                        f2bf(acc[mj * 4 + ni][r]);
                }
            }
    }
}

// ---------------------------------------------------------------------------
// Flash attention v5: R12 double-buffered pipeline + XCD-chunked block
// swizzle.  1D grid 256; swz=(bid&7)*32+(bid>>3) (bijective) -> XCD x hosts
// bh in [4x,4x+4), all 8 i-tiles: the 8 sibling blocks of one bh run in
// lockstep on one XCD, so K/V is fetched from HBM once and L2-shared
// (64 MB -> ~8 MB K/V traffic).
// ---------------------------------------------------------------------------
__global__ __launch_bounds__(256) void attn_mfma(const u16* __restrict__ qb,
                                                 const u16* __restrict__ kb,
                                                 const u16* __restrict__ vT,
                                                 const float* __restrict__ spd,
                                                 const float* __restrict__ head_keep,
                                                 u16* __restrict__ ab) {
    __shared__ u16 Qs[128][72];
    __shared__ u16 Kd[2][64][72];
    __shared__ u16 Vd[2][64][72];
    __shared__ float Sd[2][128][65];

    const int t = threadIdx.x, lane = t & 63, w = t >> 6;
    const int hi = lane >> 5, li = lane & 31;
    const int bid = blockIdx.x;
    const int swz = (bid & 7) * 32 + (bid >> 3);   // 256 = 8*32, bijective
    const int bh = swz >> 3, it = swz & 7;
    const int b = bh >> 3, h = bh & 7;
    const int i0 = it * 128;

    const u16* qh = qb + (size_t)bh * NSEQ * DHEAD;
    const u16* kh = kb + (size_t)bh * NSEQ * DHEAD;
    const u16* vh = vT + (size_t)bh * DHEAD * NSEQ;
    const float* sp = spd + (size_t)bh * NSEQ * NSEQ;

    // Q tile [128][64]
    #pragma unroll
    for (int rep = 0; rep < 4; ++rep) {
        int row = rep * 32 + (t >> 3), c8 = (t & 7) * 8;
        *(short8*)&Qs[row][c8] = *(const short8*)&qh[(size_t)(i0 + row) * DHEAD + c8];
    }

    const int krow = t >> 3, kc8 = (t & 7) * 8;
    const int srow = t >> 4, sc = (t & 15) * 4;

    short8 rk[2], rv[2];
    float4 rs[8];
    // tile 0 load + stage into buf0
    #pragma unroll
    for (int rep = 0; rep < 2; ++rep) {
        rk[rep] = *(const short8*)&kh[(size_t)(rep * 32 + krow) * DHEAD + kc8];
        rv[rep] = *(const short8*)&vh[(size_t)(rep * 32 + krow) * NSEQ + kc8];
    }
    #pragma unroll
    for (int rep = 0; rep < 8; ++rep)
        rs[rep] = *(const float4*)&sp[(size_t)(i0 + rep * 16 + srow) * NSEQ + sc];
    #pragma unroll
    for (int rep = 0; rep < 2; ++rep) {
        *(short8*)&Kd[0][rep * 32 + krow][kc8] = rk[rep];
        *(short8*)&Vd[0][rep * 32 + krow][kc8] = rv[rep];
    }
    #pragma unroll
    for (int rep = 0; rep < 8; ++rep) {
        int rrow = rep * 16 + srow;
        Sd[0][rrow][sc + 0] = rs[rep].x * LOG2E;
        Sd[0][rrow][sc + 1] = rs[rep].y * LOG2E;
        Sd[0][rrow][sc + 2] = rs[rep].z * LOG2E;
        Sd[0][rrow][sc + 3] = rs[rep].w * LOG2E;
    }
    // issue tile-1 loads (fly across the barrier and iteration-0 compute)
    #pragma unroll
    for (int rep = 0; rep < 2; ++rep) {
        rk[rep] = *(const short8*)&kh[(size_t)(64 + rep * 32 + krow) * DHEAD + kc8];
        rv[rep] = *(const short8*)&vh[(size_t)(rep * 32 + krow) * NSEQ + 64 + kc8];
    }
    #pragma unroll
    for (int rep = 0; rep < 8; ++rep)
        rs[rep] = *(const float4*)&sp[(size_t)(i0 + rep * 16 + srow) * NSEQ + 64 + sc];
    __syncthreads();

    float m_s = -1e30f, l_s = 0.f;
    f32x16 o0 = {}, o1 = {};
    #pragma unroll
    for (int r = 0; r < 16; ++r) { o0[r] = 0.f; o1[r] = 0.f; }

    for (int jt = 0; jt < 16; ++jt) {
        const int cur = jt & 1;

        // ---- compute tile jt from buf[cur] ----
        f32x16 s2[2];
        #pragma unroll
        for (int kg = 0; kg < 2; ++kg) {
            #pragma unroll
            for (int r = 0; r < 16; ++r) s2[kg][r] = 0.f;
            #pragma unroll
            for (int ds = 0; ds < 4; ++ds) {
                short8 ak = *(const short8*)&Kd[cur][kg * 32 + li][ds * 16 + hi * 8];
                short8 bq = *(const short8*)&Qs[w * 32 + li][ds * 16 + hi * 8];
                s2[kg] = mfma32(ak, bq, s2[kg]);
            }
        }

        float p2[32];
        #pragma unroll
        for (int kg = 0; kg < 2; ++kg)
            #pragma unroll
            for (int r = 0; r < 16; ++r) {
                int key = kg * 32 + (r & 3) + 8 * (r >> 2) + 4 * hi;
                p2[kg * 16 + r] = fmaf(s2[kg][r], SCALE * LOG2E, Sd[cur][w * 32 + li][key]);
            }
        float m16[16];
        #pragma unroll
        for (int r = 0; r < 16; ++r) m16[r] = fmaxf(p2[r], p2[r + 16]);
        float m8v[8];
        #pragma unroll
        for (int r = 0; r < 8; ++r) m8v[r] = fmaxf(m16[r], m16[r + 8]);
        float m4v[4];
        #pragma unroll
        for (int r = 0; r < 4; ++r) m4v[r] = fmaxf(m8v[r], m8v[r + 4]);
        float pmax = fmaxf(fmaxf(m4v[0], m4v[1]), fmaxf(m4v[2], m4v[3]));
        pmax = fmaxf(pmax, __shfl_xor(pmax, 32));

        if (!__all(pmax <= m_s + 12.0f)) {
            float mnew = fmaxf(m_s, pmax);
            float fac = exp2_fast(m_s - mnew);
            m_s = mnew;
            l_s *= fac;
            #pragma unroll
            for (int r = 0; r < 16; ++r) {
                int ip = (r & 3) + 8 * (r >> 2) + 4 * hi;
                float fr = __shfl(fac, ip);
                o0[r] *= fr; o1[r] *= fr;
            }
        }

        float p[32];
        float sa0 = 0.f, sa1 = 0.f, sa2 = 0.f, sa3 = 0.f;
        #pragma unroll
        for (int r = 0; r < 32; r += 4) {
            p[r + 0] = exp2_fast(p2[r + 0] - m_s); sa0 += p[r + 0];
            p[r + 1] = exp2_fast(p2[r + 1] - m_s); sa1 += p[r + 1];
            p[r + 2] = exp2_fast(p2[r + 2] - m_s); sa2 += p[r + 2];
            p[r + 3] = exp2_fast(p2[r + 3] - m_s); sa3 += p[r + 3];
        }
        float rsum = (sa0 + sa1) + (sa2 + sa3);
        rsum += __shfl_xor(rsum, 32);
        l_s += rsum;

        short8 pf[4];
        #pragma unroll
        for (int ks = 0; ks < 4; ++ks) {
            int rb = (ks >> 1) * 16 + (ks & 1) * 8;
            u32 a0 = pk2(p[rb + 0], p[rb + 1]);
            u32 a1 = pk2(p[rb + 2], p[rb + 3]);
            u32 a2 = pk2(p[rb + 4], p[rb + 5]);
            u32 a3 = pk2(p[rb + 6], p[rb + 7]);
            u32 x0 = (u32)__shfl_xor((int)a0, 32);
            u32 x1 = (u32)__shfl_xor((int)a1, 32);
            u32 x2 = (u32)__shfl_xor((int)a2, 32);
            u32 x3 = (u32)__shfl_xor((int)a3, 32);
            union { u32 u[4]; short8 v; } c4;
            c4.u[0] = hi ? x2 : a0;
            c4.u[1] = hi ? x3 : a1;
            c4.u[2] = hi ? a2 : x0;
            c4.u[3] = hi ? a3 : x1;
            pf[ks] = c4.v;
        }

        #pragma unroll
        for (int ks = 0; ks < 4; ++ks) {
            short8 v0f = *(const short8*)&Vd[cur][li][ks * 16 + hi * 8];
            short8 v1f = *(const short8*)&Vd[cur][32 + li][ks * 16 + hi * 8];
            o0 = mfma32(pf[ks], v0f, o0);
            o1 = mfma32(pf[ks], v1f, o1);
        }

        // ---- stage tile jt+1 into buf[cur^1]; issue tile jt+2 loads ----
        if (jt < 15) {
            const int nxt = cur ^ 1;
            #pragma unroll
            for (int rep = 0; rep < 2; ++rep) {
                *(short8*)&Kd[nxt][rep * 32 + krow][kc8] = rk[rep];
                *(short8*)&Vd[nxt][rep * 32 + krow][kc8] = rv[rep];
            }
            #pragma unroll
            for (int rep = 0; rep < 8; ++rep) {
                int rrow = rep * 16 + srow;
                Sd[nxt][rrow][sc + 0] = rs[rep].x * LOG2E;
                Sd[nxt][rrow][sc + 1] = rs[rep].y * LOG2E;
                Sd[nxt][rrow][sc + 2] = rs[rep].z * LOG2E;
                Sd[nxt][rrow][sc + 3] = rs[rep].w * LOG2E;
            }
            if (jt < 14) {
                int j0n = (jt + 2) * 64;
                #pragma unroll
                for (int rep = 0; rep < 2; ++rep) {
                    rk[rep] = *(const short8*)&kh[(size_t)(j0n + rep * 32 + krow) * DHEAD + kc8];
                    rv[rep] = *(const short8*)&vh[(size_t)(rep * 32 + krow) * NSEQ + j0n + kc8];
                }
                #pragma unroll
                for (int rep = 0; rep < 8; ++rep)
                    rs[rep] = *(const float4*)&sp[(size_t)(i0 + rep * 16 + srow) * NSEQ + j0n + sc];
            }
            __syncthreads();
        }
    }

    // epilogue
    float ksum = 0.f;
    #pragma unroll
    for (int i = 0; i < HEADS; ++i) ksum += head_keep[i];
    const float hscale = head_keep[h] * (float)HEADS / ksum;
    const float inv = hscale / l_s;
    #pragma unroll
    for (int r = 0; r < 16; ++r) {
        int ip = (r & 3) + 8 * (r >> 2) + 4 * hi;
        float invr = __shfl(inv, ip);
        int tok = i0 + w * 32 + ip;
        size_t base = ((size_t)(b * NSEQ) + tok) * 512 + h * DHEAD;
        ab[base + li]      = f2bf(o0[r] * invr);
        ab[base + 32 + li] = f2bf(o1[r] * invr);
    }
}

// ---------------------------------------------------------------------------
// GEMM out (R7-exact): BM=64 x BN=64, BK=32, grid 8x64 = 512 blocks.
// ---------------------------------------------------------------------------
__global__ __launch_bounds__(256) void gemm_out_mfma(const u16* __restrict__ abuf,
                                                     const u16* __restrict__ wT,
                                                     const float* __restrict__ bias,
                                                     float* __restrict__ out) {
    __shared__ u16 As[64][40];
    __shared__ u16 Bs[64][40];
    const int t = threadIdx.x, lane = t & 63, w = t >> 6;
    const int wm = w >> 1, wn = w & 1;
    const int l15 = lane & 15, l4 = lane >> 4;
    const int j0 = blockIdx.x * 64, i0 = blockIdx.y * 64;

    f32x4 acc[2][2];
    #pragma unroll
    for (int m = 0; m < 2; ++m)
        #pragma unroll
        for (int n = 0; n < 2; ++n) acc[m][n] = (f32x4){0.f, 0.f, 0.f, 0.f};

    short8 rav, rbv;
    {
        int row = t >> 2, c8 = (t & 3) * 8;
        rav = *(const short8*)&abuf[(size_t)(i0 + row) * 512 + c8];
        rbv = *(const short8*)&wT[(size_t)(j0 + row) * 512 + c8];
    }

    for (int kt = 0; kt < 16; ++kt) {
        __syncthreads();
        {
            int row = t >> 2, c8 = (t & 3) * 8;
            *(short8*)&As[row][c8] = rav;
            *(short8*)&Bs[row][c8] = rbv;
        }
        __syncthreads();
        if (kt < 15) {
            int k0 = (kt + 1) * 32;
            int row = t >> 2, c8 = (t & 3) * 8;
            rav = *(const short8*)&abuf[(size_t)(i0 + row) * 512 + k0 + c8];
            rbv = *(const short8*)&wT[(size_t)(j0 + row) * 512 + k0 + c8];
        }
        short8 af[2], bf[2];
        #pragma unroll
        for (int m = 0; m < 2; ++m)
            af[m] = *(const short8*)&As[wm * 32 + m * 16 + l15][l4 * 8];
        #pragma unroll
        for (int n = 0; n < 2; ++n)
            bf[n] = *(const short8*)&Bs[wn * 32 + n * 16 + l15][l4 * 8];
        #pragma unroll
        for (int m = 0; m < 2; ++m)
            #pragma unroll
            for (int n = 0; n < 2; ++n)
                acc[m][n] = mfma16(af[m], bf[n], acc[m][n]);
    }

    #pragma unroll
    for (int m = 0; m < 2; ++m)
        #pragma unroll
        for (int n = 0; n < 2; ++n) {
            int col = j0 + wn * 32 + n * 16 + l15;
            float bb = bias[col];
            #pragma unroll
            for (int r = 0; r < 4; ++r) {
                int row = i0 + wm * 32 + m * 16 + l4 * 4 + r;
                out[(size_t)row * 512 + col] = acc[m][n][r] + bb;
            }
        }
}

extern "C" void kernel_launch(void* const* d_in, const int* in_sizes, int n_in,
                              void* d_out, int out_size, void* d_ws, size_t ws_size,
                              hipStream_t stream) {
    const float* x         = (const float*)d_in[0];
    const float* spd       = (const float*)d_in[1];
    const float* head_keep = (const float*)d_in[2];
    const float* w_qkv     = (const float*)d_in[3];
    const float* w_out     = (const float*)d_in[4];
    const float* b_out     = (const float*)d_in[5];
    float* out = (float*)d_out;

    char* ws = (char*)d_ws;
    u16* x_bf   = (u16*)(ws);                       // 4096*512
    u16* wqkvT  = (u16*)(ws + (4u << 20));          // 1536*512
    u16* woutT  = (u16*)(ws + (4u << 20) + 1572864);// 512*512
    u16* qb     = (u16*)(ws + (6u << 20));          // 32*1024*64
    u16* kb     = (u16*)(ws + (10u << 20));
    u16* vT     = (u16*)(ws + (14u << 20));
    u16* ab     = (u16*)(ws + (18u << 20));         // 4096*512

    prep<<<1280, 256, 0, stream>>>(x, w_qkv, w_out, x_bf, wqkvT, woutT);
    gemm_qkv_mfma<<<dim3(24, 32), 256, 0, stream>>>(x_bf, wqkvT, qb, kb, vT);
    attn_mfma<<<256, 256, 0, stream>>>(qb, kb, vT, spd, head_keep, ab);
    gemm_out_mfma<<<dim3(8, 64), 256, 0, stream>>>(ab, woutT, b_out, out);
}

// Round 14
// 62.698 us; speedup vs baseline: 1.1496x; 1.0329x over previous
//
#include <hip/hip_runtime.h>
#include <math.h>

#define NSEQ   1024
#define HEADS  8
#define DHEAD  64
#define SCALE  0.125f
#define LOG2E  1.4426950408889634f

typedef unsigned int u32;
typedef unsigned short u16;
typedef short short8 __attribute__((ext_vector_type(8)));   // 8 bf16 (4 VGPRs)
typedef __bf16 bf16x2 __attribute__((ext_vector_type(2)));
typedef __bf16 bf16x8 __attribute__((ext_vector_type(8)));
typedef float f32x4  __attribute__((ext_vector_type(4)));
typedef float f32x16 __attribute__((ext_vector_type(16)));

__device__ __forceinline__ u16 f2bf(float f) {
    __bf16 h = (__bf16)f;
    return __builtin_bit_cast(u16, h);
}
__device__ __forceinline__ u32 pk2(float lo, float hi) {
    bf16x2 v; v[0] = (__bf16)lo; v[1] = (__bf16)hi;
    return __builtin_bit_cast(u32, v);
}
// no inline-asm exp (R6 lesson: unscheduled TRANS hazard -> nondeterminism)
__device__ __forceinline__ float exp2_fast(float x) {
#if __has_builtin(__builtin_amdgcn_exp2f)
    return __builtin_amdgcn_exp2f(x);
#else
    return exp2f(x);
#endif
}
__device__ __forceinline__ f32x4 mfma16(short8 a, short8 b, f32x4 c) {
    return __builtin_amdgcn_mfma_f32_16x16x32_bf16(a, b, c, 0, 0, 0);
}
__device__ __forceinline__ f32x16 mfma32(short8 a, short8 b, f32x16 c) {
    return __builtin_amdgcn_mfma_f32_32x32x16_bf16(a, b, c, 0, 0, 0);
}

// ---------------------------------------------------------------------------
// prep (R13-exact): x->bf16 convert + both weight transpose-converts.
// blocks [0,1024): conv x; [1024,1216): w_qkv^T; [1216,1280): w_out^T.
// ---------------------------------------------------------------------------
__global__ __launch_bounds__(256) void prep(const float* __restrict__ x,
                                            const float* __restrict__ wqkv,
                                            const float* __restrict__ wout,
                                            u16* __restrict__ x_bf,
                                            u16* __restrict__ wqkvT,
                                            u16* __restrict__ woutT) {
    __shared__ float T[64][65];
    const int t = threadIdx.x;
    const int bb = blockIdx.x;
    if (bb < 1024) {
        int i = (bb * 256 + t) * 8;
        float4 a = *(const float4*)&x[i];
        float4 b = *(const float4*)&x[i + 4];
        bf16x8 v;
        v[0] = (__bf16)a.x; v[1] = (__bf16)a.y; v[2] = (__bf16)a.z; v[3] = (__bf16)a.w;
        v[4] = (__bf16)b.x; v[5] = (__bf16)b.y; v[6] = (__bf16)b.z; v[7] = (__bf16)b.w;
        *(short8*)&x_bf[i] = __builtin_bit_cast(short8, v);
        return;
    }
    const float* in; u16* outp; int K, N, n0, k0;
    if (bb < 1216) {
        int bid = bb - 1024;
        in = wqkv; outp = wqkvT; K = 512; N = 1536;
        n0 = (bid % 24) * 64; k0 = (bid / 24) * 64;
    } else {
        int bid = bb - 1216;
        in = wout; outp = woutT; K = 512; N = 512;
        n0 = (bid % 8) * 64; k0 = (bid / 8) * 64;
    }
    #pragma unroll
    for (int rep = 0; rep < 4; ++rep) {
        int r = rep * 16 + (t >> 4), c = (t & 15) * 4;
        float4 v = *(const float4*)&in[(size_t)(k0 + r) * N + n0 + c];
        T[r][c + 0] = v.x; T[r][c + 1] = v.y; T[r][c + 2] = v.z; T[r][c + 3] = v.w;
    }
    __syncthreads();
    const int nl = t >> 2, kb = (t & 3) * 16;
    bf16x8 s0, s1;
    #pragma unroll
    for (int e = 0; e < 8; ++e) s0[e] = (__bf16)T[kb + e][nl];
    #pragma unroll
    for (int e = 0; e < 8; ++e) s1[e] = (__bf16)T[kb + 8 + e][nl];
    *(short8*)&outp[(size_t)(n0 + nl) * K + k0 + kb]     = __builtin_bit_cast(short8, s0);
    *(short8*)&outp[(size_t)(n0 + nl) * K + k0 + kb + 8] = __builtin_bit_cast(short8, s1);
}

// ---------------------------------------------------------------------------
// GEMM qkv: C = x_bf[4096,512] @ w (wT[1536][512] bf16).  BM=128 x BN=64,
// BK=64 (8 kt, 2 MFMA-subphases each -> half the barriers of BK=32).
// 1D grid 768, XCD-chunked swizzle: XCD x owns i-panels [4x,4x+4) x all 24 j
// (A-panels 512KB + wT 1.5MB fit one L2).  v path writes C^T -> vT[b,h,d,n].
// ---------------------------------------------------------------------------
__global__ __launch_bounds__(256) void gemm_qkv_mfma(const u16* __restrict__ xb,
                                                     const u16* __restrict__ wT,
                                                     u16* __restrict__ qb,
                                                     u16* __restrict__ kb,
                                                     u16* __restrict__ vT) {
    __shared__ u16 As[128][72];
    __shared__ u16 Bs[64][72];
    const int t = threadIdx.x, lane = t & 63, w = t >> 6;
    const int wm = w >> 1, wn = w & 1;
    const int l15 = lane & 15, l4 = lane >> 4;
    const int bid = blockIdx.x;
    const int swz = (bid & 7) * 96 + (bid >> 3);      // 768 = 8*96, bijective
    const int j0 = (swz % 24) * 64, i0 = (swz / 24) * 128;
    const int which = j0 / 512;           // 0=q 1=k 2=v (uniform per block)
    const int b = i0 >> 10;

    f32x4 acc[8];
    #pragma unroll
    for (int i = 0; i < 8; ++i) acc[i] = (f32x4){0.f, 0.f, 0.f, 0.f};

    const int arow0 = t >> 2, c16 = (t & 3) * 16;

    short8 ra[4], rb2[2];
    #pragma unroll
    for (int rep = 0; rep < 2; ++rep)
        #pragma unroll
        for (int q = 0; q < 2; ++q)
            ra[rep * 2 + q] = *(const short8*)&xb[(size_t)(i0 + rep * 64 + arow0) * 512 + c16 + q * 8];
    #pragma unroll
    for (int q = 0; q < 2; ++q)
        rb2[q] = *(const short8*)&wT[(size_t)(j0 + arow0) * 512 + c16 + q * 8];

    for (int kt = 0; kt < 8; ++kt) {
        __syncthreads();
        #pragma unroll
        for (int rep = 0; rep < 2; ++rep)
            #pragma unroll
            for (int q = 0; q < 2; ++q)
                *(short8*)&As[rep * 64 + arow0][c16 + q * 8] = ra[rep * 2 + q];
        #pragma unroll
        for (int q = 0; q < 2; ++q)
            *(short8*)&Bs[arow0][c16 + q * 8] = rb2[q];
        __syncthreads();
        if (kt < 7) {
            int k0 = (kt + 1) * 64;
            #pragma unroll
            for (int rep = 0; rep < 2; ++rep)
                #pragma unroll
                for (int q = 0; q < 2; ++q)
                    ra[rep * 2 + q] = *(const short8*)&xb[(size_t)(i0 + rep * 64 + arow0) * 512 + k0 + c16 + q * 8];
            #pragma unroll
            for (int q = 0; q < 2; ++q)
                rb2[q] = *(const short8*)&wT[(size_t)(j0 + arow0) * 512 + k0 + c16 + q * 8];
        }
        #pragma unroll
        for (int ks = 0; ks < 2; ++ks) {
            if (which < 2) {
                short8 af[4], bf[2];
                #pragma unroll
                for (int m = 0; m < 4; ++m)
                    af[m] = *(const short8*)&As[wm * 64 + m * 16 + l15][ks * 32 + l4 * 8];
                #pragma unroll
                for (int n = 0; n < 2; ++n)
                    bf[n] = *(const short8*)&Bs[wn * 32 + n * 16 + l15][ks * 32 + l4 * 8];
                #pragma unroll
                for (int m = 0; m < 4; ++m)
                    #pragma unroll
                    for (int n = 0; n < 2; ++n)
                        acc[m * 2 + n] = mfma16(af[m], bf[n], acc[m * 2 + n]);
            } else {
                short8 af[2], bf[4];
                #pragma unroll
                for (int mj = 0; mj < 2; ++mj)
                    af[mj] = *(const short8*)&Bs[wn * 32 + mj * 16 + l15][ks * 32 + l4 * 8];
                #pragma unroll
                for (int ni = 0; ni < 4; ++ni)
                    bf[ni] = *(const short8*)&As[wm * 64 + ni * 16 + l15][ks * 32 + l4 * 8];
                #pragma unroll
                for (int mj = 0; mj < 2; ++mj)
                    #pragma unroll
                    for (int ni = 0; ni < 4; ++ni)
                        acc[mj * 4 + ni] = mfma16(af[mj], bf[ni], acc[mj * 4 + ni]);
            }
        }
    }

    if (which < 2) {
        u16* dst = (which == 0) ? qb : kb;
        const int h = (j0 & 511) >> 6;
        #pragma unroll
        for (int m = 0; m < 4; ++m)
            #pragma unroll
            for (int n = 0; n < 2; ++n) {
                int d = wn * 32 + n * 16 + l15;
                #pragma unroll
                for (int r = 0; r < 4; ++r) {
                    int tok = i0 + wm * 64 + m * 16 + l4 * 4 + r;
                    dst[(((size_t)(b * HEADS + h)) * NSEQ + (tok & 1023)) * DHEAD + d] =
                        f2bf(acc[m * 2 + n][r]);
                }
            }
    } else {
        const int h = (j0 - 1024) >> 6;
        #pragma unroll
        for (int mj = 0; mj < 2; ++mj)
            #pragma unroll
            for (int ni = 0; ni < 4; ++ni) {
                int tok = i0 + wm * 64 + ni * 16 + l15;
                #pragma unroll
                for (int r = 0; r < 4; ++r) {
                    int d = wn * 32 + mj * 16 + l4 * 4 + r;
                    vT[(((size_t)(b * HEADS + h)) * DHEAD + d) * NSEQ + (tok & 1023)] =
                        f2bf(acc[mj * 4 + ni][r]);
                }
            }
    }
}

// ---------------------------------------------------------------------------
// Flash attention (R13-exact): double-buffered pipeline + XCD-chunked
// swizzle.  1D grid 256; swz=(bid&7)*32+(bid>>3) -> XCD x hosts bh in
// [4x,4x+4), all 8 i-tiles (K/V L2-shared).
// ---------------------------------------------------------------------------
__global__ __launch_bounds__(256) void attn_mfma(const u16* __restrict__ qb,
                                                 const u16* __restrict__ kb,
                                                 const u16* __restrict__ vT,
                                                 const float* __restrict__ spd,
                                                 const float* __restrict__ head_keep,
                                                 u16* __restrict__ ab) {
    __shared__ u16 Qs[128][72];
    __shared__ u16 Kd[2][64][72];
    __shared__ u16 Vd[2][64][72];
    __shared__ float Sd[2][128][65];

    const int t = threadIdx.x, lane = t & 63, w = t >> 6;
    const int hi = lane >> 5, li = lane & 31;
    const int bid = blockIdx.x;
    const int swz = (bid & 7) * 32 + (bid >> 3);   // 256 = 8*32, bijective
    const int bh = swz >> 3, it = swz & 7;
    const int b = bh >> 3, h = bh & 7;
    const int i0 = it * 128;

    const u16* qh = qb + (size_t)bh * NSEQ * DHEAD;
    const u16* kh = kb + (size_t)bh * NSEQ * DHEAD;
    const u16* vh = vT + (size_t)bh * DHEAD * NSEQ;
    const float* sp = spd + (size_t)bh * NSEQ * NSEQ;

    // Q tile [128][64]
    #pragma unroll
    for (int rep = 0; rep < 4; ++rep) {
        int row = rep * 32 + (t >> 3), c8 = (t & 7) * 8;
        *(short8*)&Qs[row][c8] = *(const short8*)&qh[(size_t)(i0 + row) * DHEAD + c8];
    }

    const int krow = t >> 3, kc8 = (t & 7) * 8;
    const int srow = t >> 4, sc = (t & 15) * 4;

    short8 rk[2], rv[2];
    float4 rs[8];
    // tile 0 load + stage into buf0
    #pragma unroll
    for (int rep = 0; rep < 2; ++rep) {
        rk[rep] = *(const short8*)&kh[(size_t)(rep * 32 + krow) * DHEAD + kc8];
        rv[rep] = *(const short8*)&vh[(size_t)(rep * 32 + krow) * NSEQ + kc8];
    }
    #pragma unroll
    for (int rep = 0; rep < 8; ++rep)
        rs[rep] = *(const float4*)&sp[(size_t)(i0 + rep * 16 + srow) * NSEQ + sc];
    #pragma unroll
    for (int rep = 0; rep < 2; ++rep) {
        *(short8*)&Kd[0][rep * 32 + krow][kc8] = rk[rep];
        *(short8*)&Vd[0][rep * 32 + krow][kc8] = rv[rep];
    }
    #pragma unroll
    for (int rep = 0; rep < 8; ++rep) {
        int rrow = rep * 16 + srow;
        Sd[0][rrow][sc + 0] = rs[rep].x * LOG2E;
        Sd[0][rrow][sc + 1] = rs[rep].y * LOG2E;
        Sd[0][rrow][sc + 2] = rs[rep].z * LOG2E;
        Sd[0][rrow][sc + 3] = rs[rep].w * LOG2E;
    }
    // issue tile-1 loads (fly across the barrier and iteration-0 compute)
    #pragma unroll
    for (int rep = 0; rep < 2; ++rep) {
        rk[rep] = *(const short8*)&kh[(size_t)(64 + rep * 32 + krow) * DHEAD + kc8];
        rv[rep] = *(const short8*)&vh[(size_t)(rep * 32 + krow) * NSEQ + 64 + kc8];
    }
    #pragma unroll
    for (int rep = 0; rep < 8; ++rep)
        rs[rep] = *(const float4*)&sp[(size_t)(i0 + rep * 16 + srow) * NSEQ + 64 + sc];
    __syncthreads();

    float m_s = -1e30f, l_s = 0.f;
    f32x16 o0 = {}, o1 = {};
    #pragma unroll
    for (int r = 0; r < 16; ++r) { o0[r] = 0.f; o1[r] = 0.f; }

    for (int jt = 0; jt < 16; ++jt) {
        const int cur = jt & 1;

        // ---- compute tile jt from buf[cur] ----
        f32x16 s2[2];
        #pragma unroll
        for (int kg = 0; kg < 2; ++kg) {
            #pragma unroll
            for (int r = 0; r < 16; ++r) s2[kg][r] = 0.f;
            #pragma unroll
            for (int ds = 0; ds < 4; ++ds) {
                short8 ak = *(const short8*)&Kd[cur][kg * 32 + li][ds * 16 + hi * 8];
                short8 bq = *(const short8*)&Qs[w * 32 + li][ds * 16 + hi * 8];
                s2[kg] = mfma32(ak, bq, s2[kg]);
            }
        }

        float p2[32];
        #pragma unroll
        for (int kg = 0; kg < 2; ++kg)
            #pragma unroll
            for (int r = 0; r < 16; ++r) {
                int key = kg * 32 + (r & 3) + 8 * (r >> 2) + 4 * hi;
                p2[kg * 16 + r] = fmaf(s2[kg][r], SCALE * LOG2E, Sd[cur][w * 32 + li][key]);
            }
        float m16[16];
        #pragma unroll
        for (int r = 0; r < 16; ++r) m16[r] = fmaxf(p2[r], p2[r + 16]);
        float m8v[8];
        #pragma unroll
        for (int r = 0; r < 8; ++r) m8v[r] = fmaxf(m16[r], m16[r + 8]);
        float m4v[4];
        #pragma unroll
        for (int r = 0; r < 4; ++r) m4v[r] = fmaxf(m8v[r], m8v[r + 4]);
        float pmax = fmaxf(fmaxf(m4v[0], m4v[1]), fmaxf(m4v[2], m4v[3]));
        pmax = fmaxf(pmax, __shfl_xor(pmax, 32));

        if (!__all(pmax <= m_s + 12.0f)) {
            float mnew = fmaxf(m_s, pmax);
            float fac = exp2_fast(m_s - mnew);
            m_s = mnew;
            l_s *= fac;
            #pragma unroll
            for (int r = 0; r < 16; ++r) {
                int ip = (r & 3) + 8 * (r >> 2) + 4 * hi;
                float fr = __shfl(fac, ip);
                o0[r] *= fr; o1[r] *= fr;
            }
        }

        float p[32];
        float sa0 = 0.f, sa1 = 0.f, sa2 = 0.f, sa3 = 0.f;
        #pragma unroll
        for (int r = 0; r < 32; r += 4) {
            p[r + 0] = exp2_fast(p2[r + 0] - m_s); sa0 += p[r + 0];
            p[r + 1] = exp2_fast(p2[r + 1] - m_s); sa1 += p[r + 1];
            p[r + 2] = exp2_fast(p2[r + 2] - m_s); sa2 += p[r + 2];
            p[r + 3] = exp2_fast(p2[r + 3] - m_s); sa3 += p[r + 3];
        }
        float rsum = (sa0 + sa1) + (sa2 + sa3);
        rsum += __shfl_xor(rsum, 32);
        l_s += rsum;

        short8 pf[4];
        #pragma unroll
        for (int ks = 0; ks < 4; ++ks) {
            int rb = (ks >> 1) * 16 + (ks & 1) * 8;
            u32 a0 = pk2(p[rb + 0], p[rb + 1]);
            u32 a1 = pk2(p[rb + 2], p[rb + 3]);
            u32 a2 = pk2(p[rb + 4], p[rb + 5]);
            u32 a3 = pk2(p[rb + 6], p[rb + 7]);
            u32 x0 = (u32)__shfl_xor((int)a0, 32);
            u32 x1 = (u32)__shfl_xor((int)a1, 32);
            u32 x2 = (u32)__shfl_xor((int)a2, 32);
            u32 x3 = (u32)__shfl_xor((int)a3, 32);
            union { u32 u[4]; short8 v; } c4;
            c4.u[0] = hi ? x2 : a0;
            c4.u[1] = hi ? x3 : a1;
            c4.u[2] = hi ? a2 : x0;
            c4.u[3] = hi ? a3 : x1;
            pf[ks] = c4.v;
        }

        #pragma unroll
        for (int ks = 0; ks < 4; ++ks) {
            short8 v0f = *(const short8*)&Vd[cur][li][ks * 16 + hi * 8];
            short8 v1f = *(const short8*)&Vd[cur][32 + li][ks * 16 + hi * 8];
            o0 = mfma32(pf[ks], v0f, o0);
            o1 = mfma32(pf[ks], v1f, o1);
        }

        // ---- stage tile jt+1 into buf[cur^1]; issue tile jt+2 loads ----
        if (jt < 15) {
            const int nxt = cur ^ 1;
            #pragma unroll
            for (int rep = 0; rep < 2; ++rep) {
                *(short8*)&Kd[nxt][rep * 32 + krow][kc8] = rk[rep];
                *(short8*)&Vd[nxt][rep * 32 + krow][kc8] = rv[rep];
            }
            #pragma unroll
            for (int rep = 0; rep < 8; ++rep) {
                int rrow = rep * 16 + srow;
                Sd[nxt][rrow][sc + 0] = rs[rep].x * LOG2E;
                Sd[nxt][rrow][sc + 1] = rs[rep].y * LOG2E;
                Sd[nxt][rrow][sc + 2] = rs[rep].z * LOG2E;
                Sd[nxt][rrow][sc + 3] = rs[rep].w * LOG2E;
            }
            if (jt < 14) {
                int j0n = (jt + 2) * 64;
                #pragma unroll
                for (int rep = 0; rep < 2; ++rep) {
                    rk[rep] = *(const short8*)&kh[(size_t)(j0n + rep * 32 + krow) * DHEAD + kc8];
                    rv[rep] = *(const short8*)&vh[(size_t)(rep * 32 + krow) * NSEQ + j0n + kc8];
                }
                #pragma unroll
                for (int rep = 0; rep < 8; ++rep)
                    rs[rep] = *(const float4*)&sp[(size_t)(i0 + rep * 16 + srow) * NSEQ + j0n + sc];
            }
            __syncthreads();
        }
    }

    // epilogue
    float ksum = 0.f;
    #pragma unroll
    for (int i = 0; i < HEADS; ++i) ksum += head_keep[i];
    const float hscale = head_keep[h] * (float)HEADS / ksum;
    const float inv = hscale / l_s;
    #pragma unroll
    for (int r = 0; r < 16; ++r) {
        int ip = (r & 3) + 8 * (r >> 2) + 4 * hi;
        float invr = __shfl(inv, ip);
        int tok = i0 + w * 32 + ip;
        size_t base = ((size_t)(b * NSEQ) + tok) * 512 + h * DHEAD;
        ab[base + li]      = f2bf(o0[r] * invr);
        ab[base + 32 + li] = f2bf(o1[r] * invr);
    }
}

// ---------------------------------------------------------------------------
// GEMM out: out[4096,512] = abuf_bf @ woutT + bias.  BM=64 x BN=64, BK=64
// (8 kt).  1D grid 512, XCD-chunked swizzle (64 blocks/XCD = 8 i x 8 j).
// ---------------------------------------------------------------------------
__global__ __launch_bounds__(256) void gemm_out_mfma(const u16* __restrict__ abuf,
                                                     const u16* __restrict__ wT,
                                                     const float* __restrict__ bias,
                                                     float* __restrict__ out) {
    __shared__ u16 As[64][72];
    __shared__ u16 Bs[64][72];
    const int t = threadIdx.x, lane = t & 63, w = t >> 6;
    const int wm = w >> 1, wn = w & 1;
    const int l15 = lane & 15, l4 = lane >> 4;
    const int bid = blockIdx.x;
    const int swz = (bid & 7) * 64 + (bid >> 3);      // 512 = 8*64, bijective
    const int j0 = (swz % 8) * 64, i0 = (swz / 8) * 64;

    f32x4 acc[2][2];
    #pragma unroll
    for (int m = 0; m < 2; ++m)
        #pragma unroll
        for (int n = 0; n < 2; ++n) acc[m][n] = (f32x4){0.f, 0.f, 0.f, 0.f};

    const int row0 = t >> 2, c16 = (t & 3) * 16;
    short8 rav[2], rbv[2];
    #pragma unroll
    for (int q = 0; q < 2; ++q) {
        rav[q] = *(const short8*)&abuf[(size_t)(i0 + row0) * 512 + c16 + q * 8];
        rbv[q] = *(const short8*)&wT[(size_t)(j0 + row0) * 512 + c16 + q * 8];
    }

    for (int kt = 0; kt < 8; ++kt) {
        __syncthreads();
        #pragma unroll
        for (int q = 0; q < 2; ++q) {
            *(short8*)&As[row0][c16 + q * 8] = rav[q];
            *(short8*)&Bs[row0][c16 + q * 8] = rbv[q];
        }
        __syncthreads();
        if (kt < 7) {
            int k0 = (kt + 1) * 64;
            #pragma unroll
            for (int q = 0; q < 2; ++q) {
                rav[q] = *(const short8*)&abuf[(size_t)(i0 + row0) * 512 + k0 + c16 + q * 8];
                rbv[q] = *(const short8*)&wT[(size_t)(j0 + row0) * 512 + k0 + c16 + q * 8];
            }
        }
        #pragma unroll
        for (int ks = 0; ks < 2; ++ks) {
            short8 af[2], bf[2];
            #pragma unroll
            for (int m = 0; m < 2; ++m)
                af[m] = *(const short8*)&As[wm * 32 + m * 16 + l15][ks * 32 + l4 * 8];
            #pragma unroll
            for (int n = 0; n < 2; ++n)
                bf[n] = *(const short8*)&Bs[wn * 32 + n * 16 + l15][ks * 32 + l4 * 8];
            #pragma unroll
            for (int m = 0; m < 2; ++m)
                #pragma unroll
                for (int n = 0; n < 2; ++n)
                    acc[m][n] = mfma16(af[m], bf[n], acc[m][n]);
        }
    }

    #pragma unroll
    for (int m = 0; m < 2; ++m)
        #pragma unroll
        for (int n = 0; n < 2; ++n) {
            int col = j0 + wn * 32 + n * 16 + l15;
            float bb = bias[col];
            #pragma unroll
            for (int r = 0; r < 4; ++r) {
                int row = i0 + wm * 32 + m * 16 + l4 * 4 + r;
                out[(size_t)row * 512 + col] = acc[m][n][r] + bb;
            }
        }
}

extern "C" void kernel_launch(void* const* d_in, const int* in_sizes, int n_in,
                              void* d_out, int out_size, void* d_ws, size_t ws_size,
                              hipStream_t stream) {
    const float* x         = (const float*)d_in[0];
    const float* spd       = (const float*)d_in[1];
    const float* head_keep = (const float*)d_in[2];
    const float* w_qkv     = (const float*)d_in[3];
    const float* w_out     = (const float*)d_in[4];
    const float* b_out     = (const float*)d_in[5];
    float* out = (float*)d_out;

    char* ws = (char*)d_ws;
    u16* x_bf   = (u16*)(ws);                       // 4096*512
    u16* wqkvT  = (u16*)(ws + (4u << 20));          // 1536*512
    u16* woutT  = (u16*)(ws + (4u << 20) + 1572864);// 512*512
    u16* qb     = (u16*)(ws + (6u << 20));          // 32*1024*64
    u16* kb     = (u16*)(ws + (10u << 20));
    u16* vT     = (u16*)(ws + (14u << 20));
    u16* ab     = (u16*)(ws + (18u << 20));         // 4096*512

    prep<<<1280, 256, 0, stream>>>(x, w_qkv, w_out, x_bf, wqkvT, woutT);
    gemm_qkv_mfma<<<768, 256, 0, stream>>>(x_bf, wqkvT, qb, kb, vT);
    attn_mfma<<<256, 256, 0, stream>>>(qb, kb, vT, spd, head_keep, ab);
    gemm_out_mfma<<<512, 256, 0, stream>>>(ab, woutT, b_out, out);
}

// Round 15
// 61.666 us; speedup vs baseline: 1.1688x; 1.0167x over previous
//
#include <hip/hip_runtime.h>
#include <math.h>

#define NSEQ   1024
#define HEADS  8
#define DHEAD  64
#define SCALE  0.125f
#define LOG2E  1.4426950408889634f

typedef unsigned int u32;
typedef unsigned short u16;
typedef short short8 __attribute__((ext_vector_type(8)));   // 8 bf16 (4 VGPRs)
typedef __bf16 bf16x2 __attribute__((ext_vector_type(2)));
typedef __bf16 bf16x8 __attribute__((ext_vector_type(8)));
typedef float f32x4  __attribute__((ext_vector_type(4)));
typedef float f32x16 __attribute__((ext_vector_type(16)));

__device__ __forceinline__ u16 f2bf(float f) {
    __bf16 h = (__bf16)f;
    return __builtin_bit_cast(u16, h);
}
__device__ __forceinline__ u32 pk2(float lo, float hi) {
    bf16x2 v; v[0] = (__bf16)lo; v[1] = (__bf16)hi;
    return __builtin_bit_cast(u32, v);
}
__device__ __forceinline__ float bf2f(u16 b) {
    u32 u = ((u32)b) << 16;
    return __builtin_bit_cast(float, u);
}
// no inline-asm exp (R6 lesson: unscheduled TRANS hazard -> nondeterminism)
__device__ __forceinline__ float exp2_fast(float x) {
#if __has_builtin(__builtin_amdgcn_exp2f)
    return __builtin_amdgcn_exp2f(x);
#else
    return exp2f(x);
#endif
}
__device__ __forceinline__ f32x4 mfma16(short8 a, short8 b, f32x4 c) {
    return __builtin_amdgcn_mfma_f32_16x16x32_bf16(a, b, c, 0, 0, 0);
}
__device__ __forceinline__ f32x16 mfma32(short8 a, short8 b, f32x16 c) {
    return __builtin_amdgcn_mfma_f32_32x32x16_bf16(a, b, c, 0, 0, 0);
}

// ---------------------------------------------------------------------------
// prep (R14-exact): x->bf16 convert + both weight transpose-converts.
// blocks [0,1024): conv x; [1024,1216): w_qkv^T; [1216,1280): w_out^T.
// ---------------------------------------------------------------------------
__global__ __launch_bounds__(256) void prep(const float* __restrict__ x,
                                            const float* __restrict__ wqkv,
                                            const float* __restrict__ wout,
                                            u16* __restrict__ x_bf,
                                            u16* __restrict__ wqkvT,
                                            u16* __restrict__ woutT) {
    __shared__ float T[64][65];
    const int t = threadIdx.x;
    const int bb = blockIdx.x;
    if (bb < 1024) {
        int i = (bb * 256 + t) * 8;
        float4 a = *(const float4*)&x[i];
        float4 b = *(const float4*)&x[i + 4];
        bf16x8 v;
        v[0] = (__bf16)a.x; v[1] = (__bf16)a.y; v[2] = (__bf16)a.z; v[3] = (__bf16)a.w;
        v[4] = (__bf16)b.x; v[5] = (__bf16)b.y; v[6] = (__bf16)b.z; v[7] = (__bf16)b.w;
        *(short8*)&x_bf[i] = __builtin_bit_cast(short8, v);
        return;
    }
    const float* in; u16* outp; int K, N, n0, k0;
    if (bb < 1216) {
        int bid = bb - 1024;
        in = wqkv; outp = wqkvT; K = 512; N = 1536;
        n0 = (bid % 24) * 64; k0 = (bid / 24) * 64;
    } else {
        int bid = bb - 1216;
        in = wout; outp = woutT; K = 512; N = 512;
        n0 = (bid % 8) * 64; k0 = (bid / 8) * 64;
    }
    #pragma unroll
    for (int rep = 0; rep < 4; ++rep) {
        int r = rep * 16 + (t >> 4), c = (t & 15) * 4;
        float4 v = *(const float4*)&in[(size_t)(k0 + r) * N + n0 + c];
        T[r][c + 0] = v.x; T[r][c + 1] = v.y; T[r][c + 2] = v.z; T[r][c + 3] = v.w;
    }
    __syncthreads();
    const int nl = t >> 2, kb = (t & 3) * 16;
    bf16x8 s0, s1;
    #pragma unroll
    for (int e = 0; e < 8; ++e) s0[e] = (__bf16)T[kb + e][nl];
    #pragma unroll
    for (int e = 0; e < 8; ++e) s1[e] = (__bf16)T[kb + 8 + e][nl];
    *(short8*)&outp[(size_t)(n0 + nl) * K + k0 + kb]     = __builtin_bit_cast(short8, s0);
    *(short8*)&outp[(size_t)(n0 + nl) * K + k0 + kb + 8] = __builtin_bit_cast(short8, s1);
}

// ---------------------------------------------------------------------------
// GEMM qkv (R14-exact): BM=128 x BN=64, BK=64, 1D grid 768 XCD-chunked.
// v path writes C^T -> vT[b,h,d,n].
// ---------------------------------------------------------------------------
__global__ __launch_bounds__(256) void gemm_qkv_mfma(const u16* __restrict__ xb,
                                                     const u16* __restrict__ wT,
                                                     u16* __restrict__ qb,
                                                     u16* __restrict__ kb,
                                                     u16* __restrict__ vT) {
    __shared__ u16 As[128][72];
    __shared__ u16 Bs[64][72];
    const int t = threadIdx.x, lane = t & 63, w = t >> 6;
    const int wm = w >> 1, wn = w & 1;
    const int l15 = lane & 15, l4 = lane >> 4;
    const int bid = blockIdx.x;
    const int swz = (bid & 7) * 96 + (bid >> 3);      // 768 = 8*96, bijective
    const int j0 = (swz % 24) * 64, i0 = (swz / 24) * 128;
    const int which = j0 / 512;           // 0=q 1=k 2=v (uniform per block)
    const int b = i0 >> 10;

    f32x4 acc[8];
    #pragma unroll
    for (int i = 0; i < 8; ++i) acc[i] = (f32x4){0.f, 0.f, 0.f, 0.f};

    const int arow0 = t >> 2, c16 = (t & 3) * 16;

    short8 ra[4], rb2[2];
    #pragma unroll
    for (int rep = 0; rep < 2; ++rep)
        #pragma unroll
        for (int q = 0; q < 2; ++q)
            ra[rep * 2 + q] = *(const short8*)&xb[(size_t)(i0 + rep * 64 + arow0) * 512 + c16 + q * 8];
    #pragma unroll
    for (int q = 0; q < 2; ++q)
        rb2[q] = *(const short8*)&wT[(size_t)(j0 + arow0) * 512 + c16 + q * 8];

    for (int kt = 0; kt < 8; ++kt) {
        __syncthreads();
        #pragma unroll
        for (int rep = 0; rep < 2; ++rep)
            #pragma unroll
            for (int q = 0; q < 2; ++q)
                *(short8*)&As[rep * 64 + arow0][c16 + q * 8] = ra[rep * 2 + q];
        #pragma unroll
        for (int q = 0; q < 2; ++q)
            *(short8*)&Bs[arow0][c16 + q * 8] = rb2[q];
        __syncthreads();
        if (kt < 7) {
            int k0 = (kt + 1) * 64;
            #pragma unroll
            for (int rep = 0; rep < 2; ++rep)
                #pragma unroll
                for (int q = 0; q < 2; ++q)
                    ra[rep * 2 + q] = *(const short8*)&xb[(size_t)(i0 + rep * 64 + arow0) * 512 + k0 + c16 + q * 8];
            #pragma unroll
            for (int q = 0; q < 2; ++q)
                rb2[q] = *(const short8*)&wT[(size_t)(j0 + arow0) * 512 + k0 + c16 + q * 8];
        }
        #pragma unroll
        for (int ks = 0; ks < 2; ++ks) {
            if (which < 2) {
                short8 af[4], bf[2];
                #pragma unroll
                for (int m = 0; m < 4; ++m)
                    af[m] = *(const short8*)&As[wm * 64 + m * 16 + l15][ks * 32 + l4 * 8];
                #pragma unroll
                for (int n = 0; n < 2; ++n)
                    bf[n] = *(const short8*)&Bs[wn * 32 + n * 16 + l15][ks * 32 + l4 * 8];
                #pragma unroll
                for (int m = 0; m < 4; ++m)
                    #pragma unroll
                    for (int n = 0; n < 2; ++n)
                        acc[m * 2 + n] = mfma16(af[m], bf[n], acc[m * 2 + n]);
            } else {
                short8 af[2], bf[4];
                #pragma unroll
                for (int mj = 0; mj < 2; ++mj)
                    af[mj] = *(const short8*)&Bs[wn * 32 + mj * 16 + l15][ks * 32 + l4 * 8];
                #pragma unroll
                for (int ni = 0; ni < 4; ++ni)
                    bf[ni] = *(const short8*)&As[wm * 64 + ni * 16 + l15][ks * 32 + l4 * 8];
                #pragma unroll
                for (int mj = 0; mj < 2; ++mj)
                    #pragma unroll
                    for (int ni = 0; ni < 4; ++ni)
                        acc[mj * 4 + ni] = mfma16(af[mj], bf[ni], acc[mj * 4 + ni]);
            }
        }
    }

    if (which < 2) {
        u16* dst = (which == 0) ? qb : kb;
        const int h = (j0 & 511) >> 6;
        #pragma unroll
        for (int m = 0; m < 4; ++m)
            #pragma unroll
            for (int n = 0; n < 2; ++n) {
                int d = wn * 32 + n * 16 + l15;
                #pragma unroll
                for (int r = 0; r < 4; ++r) {
                    int tok = i0 + wm * 64 + m * 16 + l4 * 4 + r;
                    dst[(((size_t)(b * HEADS + h)) * NSEQ + (tok & 1023)) * DHEAD + d] =
                        f2bf(acc[m * 2 + n][r]);
                }
            }
    } else {
        const int h = (j0 - 1024) >> 6;
        #pragma unroll
        for (int mj = 0; mj < 2; ++mj)
            #pragma unroll
            for (int ni = 0; ni < 4; ++ni) {
                int tok = i0 + wm * 64 + ni * 16 + l15;
                #pragma unroll
                for (int r = 0; r < 4; ++r) {
                    int d = wn * 32 + mj * 16 + l4 * 4 + r;
                    vT[(((size_t)(b * HEADS + h)) * DHEAD + d) * NSEQ + (tok & 1023)] =
                        f2bf(acc[mj * 4 + ni][r]);
                }
            }
    }
}

// ---------------------------------------------------------------------------
// Flash attention v6: R13 pipeline + 2 blocks/CU.  Q in registers (lane only
// ever reads its own row: 4 short8); spd staged as bf16 in LDS (stride-66,
// 2-way-free reads).  LDS 122 -> 69 KB; launch_bounds(256,2).
// ---------------------------------------------------------------------------
__global__ __launch_bounds__(256, 2) void attn_mfma(const u16* __restrict__ qb,
                                                    const u16* __restrict__ kb,
                                                    const u16* __restrict__ vT,
                                                    const float* __restrict__ spd,
                                                    const float* __restrict__ head_keep,
                                                    u16* __restrict__ ab) {
    __shared__ u16 Kd[2][64][72];
    __shared__ u16 Vd[2][64][72];
    __shared__ u16 Sd[2][128][66];   // bf16 spd * log2e

    const int t = threadIdx.x, lane = t & 63, w = t >> 6;
    const int hi = lane >> 5, li = lane & 31;
    const int bid = blockIdx.x;
    const int swz = (bid & 7) * 32 + (bid >> 3);   // 256 = 8*32, bijective
    const int bh = swz >> 3, it = swz & 7;
    const int b = bh >> 3, h = bh & 7;
    const int i0 = it * 128;

    const u16* qh = qb + (size_t)bh * NSEQ * DHEAD;
    const u16* kh = kb + (size_t)bh * NSEQ * DHEAD;
    const u16* vh = vT + (size_t)bh * DHEAD * NSEQ;
    const float* sp = spd + (size_t)bh * NSEQ * NSEQ;

    // Q fragments in registers: lane (w,hi,li) needs row w*32+li, elems
    // ds*16+hi*8..+7 only.
    short8 qreg[4];
    #pragma unroll
    for (int ds = 0; ds < 4; ++ds)
        qreg[ds] = *(const short8*)&qh[(size_t)(i0 + w * 32 + li) * DHEAD + ds * 16 + hi * 8];

    const int krow = t >> 3, kc8 = (t & 7) * 8;
    const int srow = t >> 4, sc = (t & 15) * 4;

    short8 rk[2], rv[2];
    float4 rs[8];
    // tile 0 load + stage into buf0
    #pragma unroll
    for (int rep = 0; rep < 2; ++rep) {
        rk[rep] = *(const short8*)&kh[(size_t)(rep * 32 + krow) * DHEAD + kc8];
        rv[rep] = *(const short8*)&vh[(size_t)(rep * 32 + krow) * NSEQ + kc8];
    }
    #pragma unroll
    for (int rep = 0; rep < 8; ++rep)
        rs[rep] = *(const float4*)&sp[(size_t)(i0 + rep * 16 + srow) * NSEQ + sc];
    #pragma unroll
    for (int rep = 0; rep < 2; ++rep) {
        *(short8*)&Kd[0][rep * 32 + krow][kc8] = rk[rep];
        *(short8*)&Vd[0][rep * 32 + krow][kc8] = rv[rep];
    }
    #pragma unroll
    for (int rep = 0; rep < 8; ++rep) {
        int rrow = rep * 16 + srow;
        *(u32*)&Sd[0][rrow][sc]     = pk2(rs[rep].x * LOG2E, rs[rep].y * LOG2E);
        *(u32*)&Sd[0][rrow][sc + 2] = pk2(rs[rep].z * LOG2E, rs[rep].w * LOG2E);
    }
    // issue tile-1 loads (fly across the barrier and iteration-0 compute)
    #pragma unroll
    for (int rep = 0; rep < 2; ++rep) {
        rk[rep] = *(const short8*)&kh[(size_t)(64 + rep * 32 + krow) * DHEAD + kc8];
        rv[rep] = *(const short8*)&vh[(size_t)(rep * 32 + krow) * NSEQ + 64 + kc8];
    }
    #pragma unroll
    for (int rep = 0; rep < 8; ++rep)
        rs[rep] = *(const float4*)&sp[(size_t)(i0 + rep * 16 + srow) * NSEQ + 64 + sc];
    __syncthreads();

    float m_s = -1e30f, l_s = 0.f;
    f32x16 o0 = {}, o1 = {};
    #pragma unroll
    for (int r = 0; r < 16; ++r) { o0[r] = 0.f; o1[r] = 0.f; }

    for (int jt = 0; jt < 16; ++jt) {
        const int cur = jt & 1;

        // ---- compute tile jt from buf[cur] ----
        f32x16 s2[2];
        #pragma unroll
        for (int kg = 0; kg < 2; ++kg) {
            #pragma unroll
            for (int r = 0; r < 16; ++r) s2[kg][r] = 0.f;
            #pragma unroll
            for (int ds = 0; ds < 4; ++ds) {
                short8 ak = *(const short8*)&Kd[cur][kg * 32 + li][ds * 16 + hi * 8];
                s2[kg] = mfma32(ak, qreg[ds], s2[kg]);
            }
        }

        float p2[32];
        #pragma unroll
        for (int kg = 0; kg < 2; ++kg)
            #pragma unroll
            for (int r = 0; r < 16; ++r) {
                int key = kg * 32 + (r & 3) + 8 * (r >> 2) + 4 * hi;
                p2[kg * 16 + r] = fmaf(s2[kg][r], SCALE * LOG2E,
                                       bf2f(Sd[cur][w * 32 + li][key]));
            }
        float m16[16];
        #pragma unroll
        for (int r = 0; r < 16; ++r) m16[r] = fmaxf(p2[r], p2[r + 16]);
        float m8v[8];
        #pragma unroll
        for (int r = 0; r < 8; ++r) m8v[r] = fmaxf(m16[r], m16[r + 8]);
        float m4v[4];
        #pragma unroll
        for (int r = 0; r < 4; ++r) m4v[r] = fmaxf(m8v[r], m8v[r + 4]);
        float pmax = fmaxf(fmaxf(m4v[0], m4v[1]), fmaxf(m4v[2], m4v[3]));
        pmax = fmaxf(pmax, __shfl_xor(pmax, 32));

        if (!__all(pmax <= m_s + 12.0f)) {
            float mnew = fmaxf(m_s, pmax);
            float fac = exp2_fast(m_s - mnew);
            m_s = mnew;
            l_s *= fac;
            #pragma unroll
            for (int r = 0; r < 16; ++r) {
                int ip = (r & 3) + 8 * (r >> 2) + 4 * hi;
                float fr = __shfl(fac, ip);
                o0[r] *= fr; o1[r] *= fr;
            }
        }

        float sa0 = 0.f, sa1 = 0.f, sa2 = 0.f, sa3 = 0.f;
        #pragma unroll
        for (int r = 0; r < 32; r += 4) {
            p2[r + 0] = exp2_fast(p2[r + 0] - m_s); sa0 += p2[r + 0];
            p2[r + 1] = exp2_fast(p2[r + 1] - m_s); sa1 += p2[r + 1];
            p2[r + 2] = exp2_fast(p2[r + 2] - m_s); sa2 += p2[r + 2];
            p2[r + 3] = exp2_fast(p2[r + 3] - m_s); sa3 += p2[r + 3];
        }
        float rsum = (sa0 + sa1) + (sa2 + sa3);
        rsum += __shfl_xor(rsum, 32);
        l_s += rsum;

        short8 pf[4];
        #pragma unroll
        for (int ks = 0; ks < 4; ++ks) {
            int rb = (ks >> 1) * 16 + (ks & 1) * 8;
            u32 a0 = pk2(p2[rb + 0], p2[rb + 1]);
            u32 a1 = pk2(p2[rb + 2], p2[rb + 3]);
            u32 a2 = pk2(p2[rb + 4], p2[rb + 5]);
            u32 a3 = pk2(p2[rb + 6], p2[rb + 7]);
            u32 x0 = (u32)__shfl_xor((int)a0, 32);
            u32 x1 = (u32)__shfl_xor((int)a1, 32);
            u32 x2 = (u32)__shfl_xor((int)a2, 32);
            u32 x3 = (u32)__shfl_xor((int)a3, 32);
            union { u32 u[4]; short8 v; } c4;
            c4.u[0] = hi ? x2 : a0;
            c4.u[1] = hi ? x3 : a1;
            c4.u[2] = hi ? a2 : x0;
            c4.u[3] = hi ? a3 : x1;
            pf[ks] = c4.v;
        }

        #pragma unroll
        for (int ks = 0; ks < 4; ++ks) {
            short8 v0f = *(const short8*)&Vd[cur][li][ks * 16 + hi * 8];
            short8 v1f = *(const short8*)&Vd[cur][32 + li][ks * 16 + hi * 8];
            o0 = mfma32(pf[ks], v0f, o0);
            o1 = mfma32(pf[ks], v1f, o1);
        }

        // ---- stage tile jt+1 into buf[cur^1]; issue tile jt+2 loads ----
        if (jt < 15) {
            const int nxt = cur ^ 1;
            #pragma unroll
            for (int rep = 0; rep < 2; ++rep) {
                *(short8*)&Kd[nxt][rep * 32 + krow][kc8] = rk[rep];
                *(short8*)&Vd[nxt][rep * 32 + krow][kc8] = rv[rep];
            }
            #pragma unroll
            for (int rep = 0; rep < 8; ++rep) {
                int rrow = rep * 16 + srow;
                *(u32*)&Sd[nxt][rrow][sc]     = pk2(rs[rep].x * LOG2E, rs[rep].y * LOG2E);
                *(u32*)&Sd[nxt][rrow][sc + 2] = pk2(rs[rep].z * LOG2E, rs[rep].w * LOG2E);
            }
            if (jt < 14) {
                int j0n = (jt + 2) * 64;
                #pragma unroll
                for (int rep = 0; rep < 2; ++rep) {
                    rk[rep] = *(const short8*)&kh[(size_t)(j0n + rep * 32 + krow) * DHEAD + kc8];
                    rv[rep] = *(const short8*)&vh[(size_t)(rep * 32 + krow) * NSEQ + j0n + kc8];
                }
                #pragma unroll
                for (int rep = 0; rep < 8; ++rep)
                    rs[rep] = *(const float4*)&sp[(size_t)(i0 + rep * 16 + srow) * NSEQ + j0n + sc];
            }
            __syncthreads();
        }
    }

    // epilogue
    float ksum = 0.f;
    #pragma unroll
    for (int i = 0; i < HEADS; ++i) ksum += head_keep[i];
    const float hscale = head_keep[h] * (float)HEADS / ksum;
    const float inv = hscale / l_s;
    #pragma unroll
    for (int r = 0; r < 16; ++r) {
        int ip = (r & 3) + 8 * (r >> 2) + 4 * hi;
        float invr = __shfl(inv, ip);
        int tok = i0 + w * 32 + ip;
        size_t base = ((size_t)(b * NSEQ) + tok) * 512 + h * DHEAD;
        ab[base + li]      = f2bf(o0[r] * invr);
        ab[base + 32 + li] = f2bf(o1[r] * invr);
    }
}

// ---------------------------------------------------------------------------
// GEMM out (R14-exact): BM=64 x BN=64, BK=64, 1D grid 512 XCD-chunked.
// ---------------------------------------------------------------------------
__global__ __launch_bounds__(256) void gemm_out_mfma(const u16* __restrict__ abuf,
                                                     const u16* __restrict__ wT,
                                                     const float* __restrict__ bias,
                                                     float* __restrict__ out) {
    __shared__ u16 As[64][72];
    __shared__ u16 Bs[64][72];
    const int t = threadIdx.x, lane = t & 63, w = t >> 6;
    const int wm = w >> 1, wn = w & 1;
    const int l15 = lane & 15, l4 = lane >> 4;
    const int bid = blockIdx.x;
    const int swz = (bid & 7) * 64 + (bid >> 3);      // 512 = 8*64, bijective
    const int j0 = (swz % 8) * 64, i0 = (swz / 8) * 64;

    f32x4 acc[2][2];
    #pragma unroll
    for (int m = 0; m < 2; ++m)
        #pragma unroll
        for (int n = 0; n < 2; ++n) acc[m][n] = (f32x4){0.f, 0.f, 0.f, 0.f};

    const int row0 = t >> 2, c16 = (t & 3) * 16;
    short8 rav[2], rbv[2];
    #pragma unroll
    for (int q = 0; q < 2; ++q) {
        rav[q] = *(const short8*)&abuf[(size_t)(i0 + row0) * 512 + c16 + q * 8];
        rbv[q] = *(const short8*)&wT[(size_t)(j0 + row0) * 512 + c16 + q * 8];
    }

    for (int kt = 0; kt < 8; ++kt) {
        __syncthreads();
        #pragma unroll
        for (int q = 0; q < 2; ++q) {
            *(short8*)&As[row0][c16 + q * 8] = rav[q];
            *(short8*)&Bs[row0][c16 + q * 8] = rbv[q];
        }
        __syncthreads();
        if (kt < 7) {
            int k0 = (kt + 1) * 64;
            #pragma unroll
            for (int q = 0; q < 2; ++q) {
                rav[q] = *(const short8*)&abuf[(size_t)(i0 + row0) * 512 + k0 + c16 + q * 8];
                rbv[q] = *(const short8*)&wT[(size_t)(j0 + row0) * 512 + k0 + c16 + q * 8];
            }
        }
        #pragma unroll
        for (int ks = 0; ks < 2; ++ks) {
            short8 af[2], bf[2];
            #pragma unroll
            for (int m = 0; m < 2; ++m)
                af[m] = *(const short8*)&As[wm * 32 + m * 16 + l15][ks * 32 + l4 * 8];
            #pragma unroll
            for (int n = 0; n < 2; ++n)
                bf[n] = *(const short8*)&Bs[wn * 32 + n * 16 + l15][ks * 32 + l4 * 8];
            #pragma unroll
            for (int m = 0; m < 2; ++m)
                #pragma unroll
                for (int n = 0; n < 2; ++n)
                    acc[m][n] = mfma16(af[m], bf[n], acc[m][n]);
        }
    }

    #pragma unroll
    for (int m = 0; m < 2; ++m)
        #pragma unroll
        for (int n = 0; n < 2; ++n) {
            int col = j0 + wn * 32 + n * 16 + l15;
            float bb = bias[col];
            #pragma unroll
            for (int r = 0; r < 4; ++r) {
                int row = i0 + wm * 32 + m * 16 + l4 * 4 + r;
                out[(size_t)row * 512 + col] = acc[m][n][r] + bb;
            }
        }
}

extern "C" void kernel_launch(void* const* d_in, const int* in_sizes, int n_in,
                              void* d_out, int out_size, void* d_ws, size_t ws_size,
                              hipStream_t stream) {
    const float* x         = (const float*)d_in[0];
    const float* spd       = (const float*)d_in[1];
    const float* head_keep = (const float*)d_in[2];
    const float* w_qkv     = (const float*)d_in[3];
    const float* w_out     = (const float*)d_in[4];
    const float* b_out     = (const float*)d_in[5];
    float* out = (float*)d_out;

    char* ws = (char*)d_ws;
    u16* x_bf   = (u16*)(ws);                       // 4096*512
    u16* wqkvT  = (u16*)(ws + (4u << 20));          // 1536*512
    u16* woutT  = (u16*)(ws + (4u << 20) + 1572864);// 512*512
    u16* qb     = (u16*)(ws + (6u << 20));          // 32*1024*64
    u16* kb     = (u16*)(ws + (10u << 20));
    u16* vT     = (u16*)(ws + (14u << 20));
    u16* ab     = (u16*)(ws + (18u << 20));         // 4096*512

    prep<<<1280, 256, 0, stream>>>(x, w_qkv, w_out, x_bf, wqkvT, woutT);
    gemm_qkv_mfma<<<768, 256, 0, stream>>>(x_bf, wqkvT, qb, kb, vT);
    attn_mfma<<<256, 256, 0, stream>>>(qb, kb, vT, spd, head_keep, ab);
    gemm_out_mfma<<<512, 256, 0, stream>>>(ab, woutT, b_out, out);
}